// Round 10
// baseline (1945.478 us; speedup 1.0000x reference)
//
#include <hip/hip_runtime.h>
#include <hip/hip_bf16.h>
#include <math.h>

#define BB 64
#define SS 512
#define HH 64
#define DD 128
#define NHD 8
#define ROWS (BB*SS)   // 32768

typedef unsigned short u16;
typedef __attribute__((ext_vector_type(8))) short bf16x8;
typedef __attribute__((ext_vector_type(4))) float f32x4;

__device__ __forceinline__ u16 f2b(float f) {
  union { float f; unsigned u; } x; x.f = f;
  unsigned r = x.u + 0x7fffu + ((x.u >> 16) & 1u);
  return (u16)(r >> 16);
}

__device__ __forceinline__ float b2f(u16 u) {
  return __uint_as_float(((unsigned)u) << 16);
}

__device__ __forceinline__ float fast_tanh(float x) {
  float ax = fminf(fabsf(x), 15.f);
  float e = __expf(2.f * ax);
  float r = 1.f - __fdividef(2.f, e + 1.f);
  return copysignf(r, x);
}

__device__ __forceinline__ void barrier_lds() {
  __builtin_amdgcn_s_waitcnt(0xC07F);   // lgkmcnt(0) only
  __builtin_amdgcn_s_barrier();
}

// ---------------------------------------------------------------------------
// SDE scan v8 — MFMA formulation. 16 blocks x 4 batches, 256 thr (4 waves).
// Each layer is a small GEMM over the 4-batch tile (M=4 rows of an M=16 MFMA,
// rows 4..15 zero). Weights live in registers as B-frags (loaded once).
// Yf stays fp32 (master state); only the MFMA input copy Yb is bf16.
// Wave roles: L1: w0,w1 drift cols 0-63/64-127; w2,w3 gate same.
//             L2: w0,w1 -> h2 cols 0-31/32-63; w2,w3 -> gc same.
//             L3: wave w -> cols w*16..w*16+15 + state update.
// ---------------------------------------------------------------------------
__global__ __launch_bounds__(256, 1) void sde_kernel(
    const float* __restrict__ ts, const float* __restrict__ noise,
    const float* __restrict__ dW1, const float* __restrict__ db1,
    const float* __restrict__ dW2, const float* __restrict__ db2,
    const float* __restrict__ dW3, const float* __restrict__ db3,
    const float* __restrict__ gW1, const float* __restrict__ gb1,
    const float* __restrict__ gW2, const float* __restrict__ gb2,
    const float* __restrict__ pmind, const float* __restrict__ pmaxd,
    float* __restrict__ out, u16* __restrict__ outB) {
  const int blk = blockIdx.x, t = threadIdx.x;
  const int w = t >> 6, lane = t & 63;
  const int fr = lane & 15, quad = lane >> 4;
  __shared__ float Yf[4][64];
  __shared__ float GC[4][64];
  __shared__ u16 Yb[16 * 72];      // bf16 A-copy of Y, rows 4..15 zero
  __shared__ u16 H1b[16 * 280];    // drift h1 @ col 0..127, gate g1 @ 136..263
  __shared__ u16 H2b[16 * 72];
  __shared__ float tl_s[512], hs_s[512], sq_s[512];

  const float mind = fabsf(pmind[0]);
  const float maxd = fabsf(pmaxd[0]);
  const bool driftW = (w < 2);
  const f32x4 z4 = {0.f, 0.f, 0.f, 0.f};

  union U8 { u16 s[8]; bf16x8 v; };

  // ---- L1 weight B-frags: W1t[col][k], col = (w&1)*64 + j*16 + fr ----
  const float* W1 = driftW ? dW1 : gW1;
  const float* B1 = driftW ? db1 : gb1;
  bf16x8 wA[4][2];
  float b1v[4], wt1[4];
  int col1[4];
#pragma unroll
  for (int j = 0; j < 4; j++) {
    col1[j] = (w & 1) * 64 + j * 16 + fr;
#pragma unroll
    for (int c = 0; c < 2; c++) {
      U8 u;
#pragma unroll
      for (int e = 0; e < 8; e++)
        u.s[e] = f2b(W1[(c * 32 + quad * 8 + e) * 128 + col1[j]]);
      wA[j][c] = u.v;
    }
    b1v[j] = B1[col1[j]];
    wt1[j] = W1[64 * 128 + col1[j]];
  }

  // ---- L2 weight B-frags: W2t[col][k], col = (w&1)*32 + j*16 + fr ----
  const float* W2 = driftW ? dW2 : gW2;
  const float* B2 = driftW ? db2 : gb2;
  bf16x8 wB[2][4];
  float b2v[2];
  int col2[2];
#pragma unroll
  for (int j = 0; j < 2; j++) {
    col2[j] = (w & 1) * 32 + j * 16 + fr;
#pragma unroll
    for (int c = 0; c < 4; c++) {
      U8 u;
#pragma unroll
      for (int e = 0; e < 8; e++)
        u.s[e] = f2b(W2[(c * 32 + quad * 8 + e) * 64 + col2[j]]);
      wB[j][c] = u.v;
    }
    b2v[j] = B2[col2[j]];
  }

  // ---- L3 weight B-frags: col = w*16 + fr ----
  const int col3 = w * 16 + fr;
  bf16x8 wC3[2];
#pragma unroll
  for (int c = 0; c < 2; c++) {
    U8 u;
#pragma unroll
    for (int e = 0; e < 8; e++)
      u.s[e] = f2b(dW3[(c * 32 + quad * 8 + e) * 64 + col3]);
    wC3[c] = u.v;
  }
  const float b3v = db3[col3];

  // ---- zero LDS (rows 4..15 of MFMA inputs must be finite) ----
  for (int idx = t; idx < 16 * 72; idx += 256) { Yb[idx] = 0; H2b[idx] = 0; }
  for (int idx = t; idx < 16 * 280; idx += 256) H1b[idx] = 0;

  // ---- times ----
  for (int idx = t; idx < 512; idx += 256) tl_s[idx] = ts[idx * 3];
  __syncthreads();
  for (int idx = t; idx < 511; idx += 256) {
    float hh = tl_s[idx + 1] - tl_s[idx];
    hs_s[idx] = hh;
    sq_s[idx] = sqrtf(hh);
  }

  // ---- y0 (256 threads = 4 batches x 64 cols) ----
  {
    const int batch = t >> 6, col = t & 63;
    const long gb = blk * 4 + batch;
    float y = 0.1f;
    if (col < 3) y = fminf(fmaxf(ts[gb * 1536 + col], 0.01f), 10.f);
    Yf[batch][col] = y;
    Yb[batch * 72 + col] = f2b(y);
    out[gb * 32768 + col] = y;
    outB[(gb * 512) * 64 + col] = f2b(y);
  }

  // ---- first noise (quad 0 lanes own the update of cols col3, rows 0..3) ----
  float nz[4] = {0.f, 0.f, 0.f, 0.f};
  if (quad == 0) {
#pragma unroll
    for (int r = 0; r < 4; r++)
      nz[r] = noise[(long)(blk * 4 + r) * 64 + col3];
  }
  __syncthreads();

  for (int i = 0; i < 511; i++) {
    // prefetch next-step noise (floats across LDS-only barriers)
    float nzn[4] = {0.f, 0.f, 0.f, 0.f};
    if (quad == 0 && i < 510) {
#pragma unroll
      for (int r = 0; r < 4; r++)
        nzn[r] = noise[(long)(i + 1) * 4096 + (blk * 4 + r) * 64 + col3];
    }
    const float tcur = tl_s[i];
    const float hh = hs_s[i];
    const float sq = sq_s[i];

    // ---- L1: H1[4x128] = tanh(Y[4x64] @ W1 + t*w_t + b) ----
    {
      bf16x8 a0 = *(const bf16x8*)&Yb[fr * 72 + quad * 8];
      bf16x8 a1 = *(const bf16x8*)&Yb[fr * 72 + 32 + quad * 8];
#pragma unroll
      for (int j = 0; j < 4; j++) {
        f32x4 acc = __builtin_amdgcn_mfma_f32_16x16x32_bf16(a0, wA[j][0], z4, 0, 0, 0);
        acc = __builtin_amdgcn_mfma_f32_16x16x32_bf16(a1, wA[j][1], acc, 0, 0, 0);
        if (quad == 0) {
          int off = (driftW ? 0 : 136) + col1[j];
#pragma unroll
          for (int r = 0; r < 4; r++) {
            float v = acc[r] + b1v[j] + tcur * wt1[j];
            H1b[r * 280 + off] = f2b(fast_tanh(v));
          }
        }
      }
    }
    barrier_lds();                        // barrier 1

    // ---- L2: h2/gc[4x64] from H1[4x128] ----
    {
      const int srcOff = driftW ? 0 : 136;
      bf16x8 hc[4];
#pragma unroll
      for (int c = 0; c < 4; c++)
        hc[c] = *(const bf16x8*)&H1b[fr * 280 + srcOff + c * 32 + quad * 8];
#pragma unroll
      for (int j = 0; j < 2; j++) {
        f32x4 acc = z4;
#pragma unroll
        for (int c = 0; c < 4; c++)
          acc = __builtin_amdgcn_mfma_f32_16x16x32_bf16(hc[c], wB[j][c], acc, 0, 0, 0);
        if (quad == 0) {
#pragma unroll
          for (int r = 0; r < 4; r++) {
            float v = acc[r] + b2v[j];
            if (driftW) {
              H2b[r * 72 + col2[j]] = f2b(fast_tanh(v));
            } else {
              GC[r][col2[j]] =
                  fmaxf(v, 0.f) + __logf(1.f + __expf(-fabsf(v))) + mind;
            }
          }
        }
      }
    }
    barrier_lds();                        // barrier 2

    // ---- L3 + update ----
    {
      bf16x8 g0 = *(const bf16x8*)&H2b[fr * 72 + quad * 8];
      bf16x8 g1 = *(const bf16x8*)&H2b[fr * 72 + 32 + quad * 8];
      f32x4 acc = __builtin_amdgcn_mfma_f32_16x16x32_bf16(g0, wC3[0], z4, 0, 0, 0);
      acc = __builtin_amdgcn_mfma_f32_16x16x32_bf16(g1, wC3[1], acc, 0, 0, 0);
      if (quad == 0) {
#pragma unroll
        for (int r = 0; r < 4; r++) {
          float dc = fminf(fmaxf(acc[r] + b3v, -maxd), maxd);
          float yo = Yf[r][col3];
          float gg = GC[r][col3] * fminf(fmaxf(yo, -10.f), 10.f);
          float yn = yo + dc * yo * hh + gg * nz[r] * sq;
          yn = fminf(fmaxf(yn, 0.01f), 10.f);
          Yf[r][col3] = yn;
          Yb[r * 72 + col3] = f2b(yn);
          long gb = blk * 4 + r;
          out[gb * 32768 + (long)(i + 1) * 64 + col3] = yn;
          outB[(gb * 512 + (long)(i + 1)) * 64 + col3] = f2b(yn);
          nz[r] = nzn[r];
        }
      }
    }
    barrier_lds();                        // barrier 3
  }
}

// ---------------------------------------------------------------------------
__global__ __launch_bounds__(256) void prep_weights(
    const float* __restrict__ in_W, const float* __restrict__ Wq,
    const float* __restrict__ Wk, const float* __restrict__ Wv,
    const float* __restrict__ Wo, const float* __restrict__ fW1,
    const float* __restrict__ fW2,
    u16* __restrict__ inWt, u16* __restrict__ qkvWt, u16* __restrict__ Wot,
    u16* __restrict__ fW1t, u16* __restrict__ fW2t) {
  const int z = blockIdx.z, layer = blockIdx.y, tile = blockIdx.x;
  const float* src; u16* dst; int R, C, nl;
  switch (z) {
    case 0: src = in_W; dst = inWt; R = 64; C = 128; nl = 1; break;
    case 1: src = Wq + layer * 16384; dst = qkvWt + layer * 49152; R = 128; C = 128; nl = 4; break;
    case 2: src = Wk + layer * 16384; dst = qkvWt + layer * 49152 + 16384; R = 128; C = 128; nl = 4; break;
    case 3: src = Wv + layer * 16384; dst = qkvWt + layer * 49152 + 32768; R = 128; C = 128; nl = 4; break;
    case 4: src = Wo + layer * 16384; dst = Wot + layer * 16384; R = 128; C = 128; nl = 4; break;
    case 5: src = fW1 + layer * 65536; dst = fW1t + layer * 65536; R = 128; C = 512; nl = 4; break;
    default: src = fW2 + layer * 65536; dst = fW2t + layer * 65536; R = 512; C = 128; nl = 4; break;
  }
  const int nt = (R / 32) * (C / 32);
  if (layer >= nl || tile >= nt) return;
  const int tpr = C / 32;
  const int r0 = (tile / tpr) * 32, c0 = (tile % tpr) * 32;
  __shared__ float tl[32][33];
  const int tx = threadIdx.x & 31, ty = threadIdx.x >> 5;
#pragma unroll
  for (int p = 0; p < 4; p++)
    tl[ty + 8 * p][tx] = src[(long)(r0 + ty + 8 * p) * C + c0 + tx];
  __syncthreads();
#pragma unroll
  for (int p = 0; p < 4; p++)
    dst[(long)(c0 + ty + 8 * p) * R + r0 + tx] = f2b(tl[tx][ty + 8 * p]);
}

// ---------------------------------------------------------------------------
// bf16 MFMA GEMM. MODE 1: bf16+relu. MODE 3: bf16.
// ---------------------------------------------------------------------------
template <int MODE>
__global__ __launch_bounds__(256) void mfma_gemm(
    const u16* __restrict__ A, const u16* __restrict__ Bt,
    const float* __restrict__ bias, u16* __restrict__ outB, int K, int N) {
  __shared__ u16 As[128 * 40];
  __shared__ u16 Bs[64 * 40];
  const int t = threadIdx.x;
  const int nb = blockIdx.x * 64;
  const long mb = (long)blockIdx.y * 128;
  const int lane = t & 63, wave = t >> 6;
  const int wm = (wave >> 1) * 64, wn = (wave & 1) * 32;
  const int fr = lane & 15, quad = lane >> 4;

  f32x4 zero = {0.f, 0.f, 0.f, 0.f};
  f32x4 acc[4][2];
#pragma unroll
  for (int mi = 0; mi < 4; mi++)
#pragma unroll
    for (int ni = 0; ni < 2; ni++) acc[mi][ni] = zero;

  for (int k0 = 0; k0 < K; k0 += 32) {
#pragma unroll
    for (int p = 0; p < 2; p++) {
      int idx = t + p * 256, row = idx >> 2, seg = idx & 3;
      int4 v = *(const int4*)&A[(mb + row) * K + k0 + seg * 8];
      *(int4*)&As[row * 40 + seg * 8] = v;
    }
    {
      int row = t >> 2, seg = t & 3;
      int4 v = *(const int4*)&Bt[(long)(nb + row) * K + k0 + seg * 8];
      *(int4*)&Bs[row * 40 + seg * 8] = v;
    }
    __syncthreads();
    bf16x8 af[4], bfr[2];
#pragma unroll
    for (int mi = 0; mi < 4; mi++)
      af[mi] = *(const bf16x8*)&As[(wm + mi * 16 + fr) * 40 + quad * 8];
#pragma unroll
    for (int ni = 0; ni < 2; ni++)
      bfr[ni] = *(const bf16x8*)&Bs[(wn + ni * 16 + fr) * 40 + quad * 8];
#pragma unroll
    for (int mi = 0; mi < 4; mi++)
#pragma unroll
      for (int ni = 0; ni < 2; ni++)
        acc[mi][ni] = __builtin_amdgcn_mfma_f32_16x16x32_bf16(
            af[mi], bfr[ni], acc[mi][ni], 0, 0, 0);
    __syncthreads();
  }

#pragma unroll
  for (int mi = 0; mi < 4; mi++)
#pragma unroll
    for (int ni = 0; ni < 2; ni++) {
      int col = nb + wn + ni * 16 + fr;
      float bv = bias[col];
#pragma unroll
      for (int r = 0; r < 4; r++) {
        long row = mb + wm + mi * 16 + quad * 4 + r;
        float v = acc[mi][ni][r] + bv;
        if (MODE == 1) {
          outB[row * N + col] = f2b(fmaxf(v, 0.f));
        } else {
          outB[row * N + col] = f2b(v);
        }
      }
    }
}

// ---------------------------------------------------------------------------
// Fused GEMM + residual(bf16) + LayerNorm -> bf16. Tile 64x128, 512 blocks.
// ---------------------------------------------------------------------------
__global__ __launch_bounds__(256) void gemm_ln(
    const u16* __restrict__ A, const u16* __restrict__ Bt,
    const float* __restrict__ bias, const u16* __restrict__ resid,
    const float* __restrict__ gamma, const float* __restrict__ beta,
    u16* __restrict__ outB, int K) {
  __shared__ u16 As[64 * 40];
  __shared__ u16 Bs[128 * 40];
  __shared__ float s1[2][64], s2[2][64];
  const int t = threadIdx.x;
  const long mb = (long)blockIdx.x * 64;
  const int lane = t & 63, wave = t >> 6;
  const int wm = (wave >> 1) * 32, wn = (wave & 1) * 64;
  const int fr = lane & 15, quad = lane >> 4;

  f32x4 zero = {0.f, 0.f, 0.f, 0.f};
  f32x4 acc[2][4];
#pragma unroll
  for (int mi = 0; mi < 2; mi++)
#pragma unroll
    for (int ni = 0; ni < 4; ni++) acc[mi][ni] = zero;

  for (int k0 = 0; k0 < K; k0 += 32) {
    {
      int row = t >> 2, seg = t & 3;
      *(int4*)&As[row * 40 + seg * 8] =
          *(const int4*)&A[(mb + row) * K + k0 + seg * 8];
    }
#pragma unroll
    for (int p = 0; p < 2; p++) {
      int idx = t + p * 256, row = idx >> 2, seg = idx & 3;
      *(int4*)&Bs[row * 40 + seg * 8] =
          *(const int4*)&Bt[(long)row * K + k0 + seg * 8];
    }
    __syncthreads();
    bf16x8 af[2], bfr[4];
#pragma unroll
    for (int mi = 0; mi < 2; mi++)
      af[mi] = *(const bf16x8*)&As[(wm + mi * 16 + fr) * 40 + quad * 8];
#pragma unroll
    for (int ni = 0; ni < 4; ni++)
      bfr[ni] = *(const bf16x8*)&Bs[(wn + ni * 16 + fr) * 40 + quad * 8];
#pragma unroll
    for (int mi = 0; mi < 2; mi++)
#pragma unroll
      for (int ni = 0; ni < 4; ni++)
        acc[mi][ni] = __builtin_amdgcn_mfma_f32_16x16x32_bf16(
            af[mi], bfr[ni], acc[mi][ni], 0, 0, 0);
    __syncthreads();
  }

  float bv[4], gv[4], be[4];
#pragma unroll
  for (int ni = 0; ni < 4; ni++) {
    int col = wn + ni * 16 + fr;
    bv[ni] = bias[col];
    gv[ni] = gamma[col];
    be[ni] = beta[col];
  }

#pragma unroll
  for (int mi = 0; mi < 2; mi++) {
#pragma unroll
    for (int r = 0; r < 4; r++) {
      int rloc = wm + mi * 16 + quad * 4 + r;
      long row = mb + rloc;
      float s = 0.f, ss = 0.f;
#pragma unroll
      for (int ni = 0; ni < 4; ni++) {
        int col = wn + ni * 16 + fr;
        float v = acc[mi][ni][r] + bv[ni] + b2f(resid[row * DD + col]);
        acc[mi][ni][r] = v;
        s += v;
        ss += v * v;
      }
      s += __shfl_xor(s, 1); ss += __shfl_xor(ss, 1);
      s += __shfl_xor(s, 2); ss += __shfl_xor(ss, 2);
      s += __shfl_xor(s, 4); ss += __shfl_xor(ss, 4);
      s += __shfl_xor(s, 8); ss += __shfl_xor(ss, 8);
      if (fr == 0) {
        s1[wn >> 6][rloc] = s;
        s2[wn >> 6][rloc] = ss;
      }
    }
  }
  __syncthreads();

#pragma unroll
  for (int mi = 0; mi < 2; mi++) {
#pragma unroll
    for (int r = 0; r < 4; r++) {
      int rloc = wm + mi * 16 + quad * 4 + r;
      long row = mb + rloc;
      float sum = s1[0][rloc] + s1[1][rloc];
      float sumsq = s2[0][rloc] + s2[1][rloc];
      float mean = sum * (1.f / 128.f);
      float var = sumsq * (1.f / 128.f) - mean * mean;
      float rstd = rsqrtf(var + 1e-5f);
#pragma unroll
      for (int ni = 0; ni < 4; ni++) {
        int col = wn + ni * 16 + fr;
        float o = (acc[mi][ni][r] - mean) * rstd * gv[ni] + be[ni];
        outB[row * DD + col] = f2b(o);
      }
    }
  }
}

// ---------------------------------------------------------------------------
// Fused QKV-projection + flash attention (verified round 9).
// ---------------------------------------------------------------------------
__global__ __launch_bounds__(256, 2) void qkv_attn(
    const u16* __restrict__ xb, const u16* __restrict__ qkvW,
    const float* __restrict__ bq, const float* __restrict__ bk,
    const float* __restrict__ bv, u16* __restrict__ Og) {
  const int bh = blockIdx.x;
  const int b = bh >> 3, h = bh & 7;
  __shared__ u16 Ks[512 * 24];
  __shared__ u16 Vt[16 * 520];
  __shared__ u16 Qs[512 * 24];
  const int t = threadIdx.x;
  const int w = t >> 6, lane = t & 63;
  const int fr = lane & 15, quad = lane >> 4;
  const long obase = ((long)b * SS) * DD + h * 16;
  const u16* xrow = xb + (long)b * SS * DD;

  const u16* Wq_h = qkvW + (h * 16) * 128;
  const u16* Wk_h = qkvW + 16384 + (h * 16) * 128;
  const u16* Wv_h = qkvW + 32768 + (h * 16) * 128;
  bf16x8 wqf[4], wkf[4], wvf[4];
#pragma unroll
  for (int c = 0; c < 4; c++) {
    wqf[c] = *(const bf16x8*)&Wq_h[fr * 128 + c * 32 + quad * 8];
    wkf[c] = *(const bf16x8*)&Wk_h[fr * 128 + c * 32 + quad * 8];
    wvf[c] = *(const bf16x8*)&Wv_h[fr * 128 + c * 32 + quad * 8];
  }
  const float bqv = bq[h * 16 + fr];
  const float bkv = bk[h * 16 + fr];
  const float bvv = bv[h * 16 + fr];
  const f32x4 z4 = {0.f, 0.f, 0.f, 0.f};

  for (int tile = w; tile < 32; tile += 4) {
    const int t0 = tile * 16;
    bf16x8 af[4];
#pragma unroll
    for (int c = 0; c < 4; c++)
      af[c] = *(const bf16x8*)&xrow[(t0 + fr) * 128 + c * 32 + quad * 8];
    f32x4 qa = z4, ka = z4, va = z4;
#pragma unroll
    for (int c = 0; c < 4; c++) {
      qa = __builtin_amdgcn_mfma_f32_16x16x32_bf16(af[c], wqf[c], qa, 0, 0, 0);
      ka = __builtin_amdgcn_mfma_f32_16x16x32_bf16(af[c], wkf[c], ka, 0, 0, 0);
      va = __builtin_amdgcn_mfma_f32_16x16x32_bf16(af[c], wvf[c], va, 0, 0, 0);
    }
#pragma unroll
    for (int r = 0; r < 4; r++) {
      int row = t0 + quad * 4 + r;
      Qs[row * 24 + fr] = f2b(qa[r] + bqv);
      Ks[row * 24 + fr] = f2b(ka[r] + bkv);
      Vt[fr * 520 + row] = f2b(va[r] + bvv);
    }
  }
  __syncthreads();

  const float scale = 0.25f;
  const int addrA = (((quad & 1) * 32) + fr) * 4;
  const int addrB = addrA + 64;
  const bool loTile = (quad < 2);

  for (int qt = w; qt < 32; qt += 4) {
    const int q0 = qt * 16;
    bf16x8 qf = {0, 0, 0, 0, 0, 0, 0, 0};
    if (quad < 2)
      qf = *(const bf16x8*)&Qs[(q0 + fr) * 24 + quad * 8];
    f32x4 oacc = {0.f, 0.f, 0.f, 0.f};
    float mrun = -1e30f, lrun = 0.f;

    for (int kt = 0; kt < 16; kt++) {
      const int k0 = kt * 32;
      bf16x8 kf0 = {0, 0, 0, 0, 0, 0, 0, 0};
      bf16x8 kf1 = {0, 0, 0, 0, 0, 0, 0, 0};
      if (quad < 2) {
        kf0 = *(const bf16x8*)&Ks[(k0 + fr) * 24 + quad * 8];
        kf1 = *(const bf16x8*)&Ks[(k0 + 16 + fr) * 24 + quad * 8];
      }
      f32x4 slo = __builtin_amdgcn_mfma_f32_16x16x32_bf16(kf0, qf, z4, 0, 0, 0);
      f32x4 shi = __builtin_amdgcn_mfma_f32_16x16x32_bf16(kf1, qf, z4, 0, 0, 0);
      float s[8];
#pragma unroll
      for (int r = 0; r < 4; r++) {
        s[r] = slo[r] * scale;
        s[4 + r] = shi[r] * scale;
      }
      float mx = s[0];
#pragma unroll
      for (int r = 1; r < 8; r++) mx = fmaxf(mx, s[r]);
      mx = fmaxf(mx, __shfl_xor(mx, 16));
      mx = fmaxf(mx, __shfl_xor(mx, 32));
      float nm = fmaxf(mrun, mx);
      float alpha = __expf(mrun - nm);
      mrun = nm;
      float p[8], rs = 0.f;
#pragma unroll
      for (int r = 0; r < 8; r++) {
        p[r] = __expf(s[r] - nm);
        rs += p[r];
      }
      rs += __shfl_xor(rs, 16);
      rs += __shfl_xor(rs, 32);
      lrun = lrun * alpha + rs;
#pragma unroll
      for (int r = 0; r < 4; r++) oacc[r] *= alpha;

      int pk0 = ((int)f2b(p[1]) << 16) | f2b(p[0]);
      int pk1 = ((int)f2b(p[3]) << 16) | f2b(p[2]);
      int pk2 = ((int)f2b(p[5]) << 16) | f2b(p[4]);
      int pk3 = ((int)f2b(p[7]) << 16) | f2b(p[6]);
      int B0a = __builtin_amdgcn_ds_bpermute(addrA, pk0);
      int B0b = __builtin_amdgcn_ds_bpermute(addrA, pk2);
      int B1a = __builtin_amdgcn_ds_bpermute(addrA, pk1);
      int B1b = __builtin_amdgcn_ds_bpermute(addrA, pk3);
      int B2a = __builtin_amdgcn_ds_bpermute(addrB, pk0);
      int B2b = __builtin_amdgcn_ds_bpermute(addrB, pk2);
      int B3a = __builtin_amdgcn_ds_bpermute(addrB, pk1);
      int B3b = __builtin_amdgcn_ds_bpermute(addrB, pk3);
      union { int i[4]; bf16x8 v; } pu;
      pu.i[0] = loTile ? B0a : B0b;
      pu.i[1] = loTile ? B1a : B1b;
      pu.i[2] = loTile ? B2a : B2b;
      pu.i[3] = loTile ? B3a : B3b;
      bf16x8 vf = *(const bf16x8*)&Vt[fr * 520 + k0 + quad * 8];
      oacc = __builtin_amdgcn_mfma_f32_16x16x32_bf16(vf, pu.v, oacc, 0, 0, 0);
    }

    float inv = __fdividef(1.f, lrun);
    ushort4 o;
    o.x = f2b(oacc[0] * inv);
    o.y = f2b(oacc[1] * inv);
    o.z = f2b(oacc[2] * inv);
    o.w = f2b(oacc[3] * inv);
    *(ushort4*)&Og[obase + (long)(q0 + fr) * DD + quad * 4] = o;
  }
}

// ---------------------------------------------------------------------------
__global__ __launch_bounds__(128) void pool_kernel(const u16* __restrict__ X,
                                                   float* __restrict__ P) {
  const int b = blockIdx.x, c = threadIdx.x;
  float acc = 0.f;
  for (int s = 0; s < SS; s++) acc += b2f(X[((long)b * SS + s) * DD + c]);
  P[b * DD + c] = acc * (1.f / 512.f);
}

__global__ __launch_bounds__(64) void cls_kernel(
    const float* __restrict__ P, const float* __restrict__ W1,
    const float* __restrict__ b1, const float* __restrict__ W2,
    const float* __restrict__ b2, float* __restrict__ L) {
  const int b = blockIdx.x, t = threadIdx.x;
  __shared__ float sp[128];
  __shared__ float sh[64];
  sp[t] = P[b * DD + t];
  sp[t + 64] = P[b * DD + 64 + t];
  __syncthreads();
  float acc = b1[t];
  for (int k = 0; k < 128; k++) acc += sp[k] * W1[k * 64 + t];
  sh[t] = fmaxf(acc, 0.f);
  __syncthreads();
  if (t < 5) {
    float acc2 = b2[t];
    for (int k = 0; k < 64; k++) acc2 += sh[k] * W2[k * 5 + t];
    L[b * 5 + t] = acc2;
  }
}

// ---------------------------------------------------------------------------
extern "C" void kernel_launch(void* const* d_in, const int* in_sizes, int n_in,
                              void* d_out, int out_size, void* d_ws, size_t ws_size,
                              hipStream_t stream) {
  const float* ts    = (const float*)d_in[0];
  const float* noise = (const float*)d_in[2];
  const float* dW1   = (const float*)d_in[3];
  const float* db1   = (const float*)d_in[4];
  const float* dW2   = (const float*)d_in[5];
  const float* db2   = (const float*)d_in[6];
  const float* dW3   = (const float*)d_in[7];
  const float* db3   = (const float*)d_in[8];
  const float* gW1   = (const float*)d_in[9];
  const float* gb1   = (const float*)d_in[10];
  const float* gW2   = (const float*)d_in[11];
  const float* gb2   = (const float*)d_in[12];
  const float* mind  = (const float*)d_in[13];
  const float* maxd  = (const float*)d_in[14];
  const float* in_W  = (const float*)d_in[15];
  const float* in_b  = (const float*)d_in[16];
  const float* Wq    = (const float*)d_in[17];
  const float* bq    = (const float*)d_in[18];
  const float* Wk    = (const float*)d_in[19];
  const float* bk    = (const float*)d_in[20];
  const float* Wv    = (const float*)d_in[21];
  const float* bv    = (const float*)d_in[22];
  const float* Wo    = (const float*)d_in[23];
  const float* bo    = (const float*)d_in[24];
  const float* ln1s  = (const float*)d_in[25];
  const float* ln1b  = (const float*)d_in[26];
  const float* fW1   = (const float*)d_in[27];
  const float* fb1   = (const float*)d_in[28];
  const float* fW2   = (const float*)d_in[29];
  const float* fb2   = (const float*)d_in[30];
  const float* ln2s  = (const float*)d_in[31];
  const float* ln2b  = (const float*)d_in[32];
  const float* cW1   = (const float*)d_in[33];
  const float* cb1   = (const float*)d_in[34];
  const float* cW2   = (const float*)d_in[35];
  const float* cb2   = (const float*)d_in[36];

  float* logits = (float*)d_out;
  float* sde    = logits + BB * 5;

  char* W = (char*)d_ws;
  u16*  bxb    = (u16*)(W);                   //  8 MB bf16 x
  u16*  bh     = (u16*)(W + (8u << 20));      // 32 MB FFN hidden
  u16*  bob    = (u16*)(W + (40u << 20));     //  8 MB bf16 attn out
  u16*  bsb    = (u16*)(W + (48u << 20));     //  4 MB bf16 sde feats
  u16*  wts    = (u16*)(W + (52u << 20));     // ~1.5 MB bf16 weights
  float* bp    = (float*)(W + (54u << 20));   // pooled 64x128

  u16* inWt  = wts;                 // [128][64]
  u16* qkvWt = inWt + 8192;         // [4][3][128][128]
  u16* Wot   = qkvWt + 196608;      // [4][128][128]
  u16* fW1t  = Wot + 65536;         // [4][512][128]
  u16* fW2t  = fW1t + 262144;       // [4][128][512]

  prep_weights<<<dim3(64, 4, 7), 256, 0, stream>>>(in_W, Wq, Wk, Wv, Wo, fW1, fW2,
                                                   inWt, qkvWt, Wot, fW1t, fW2t);

  sde_kernel<<<16, 256, 0, stream>>>(ts, noise, dW1, db1, dW2, db2, dW3, db3,
                                     gW1, gb1, gW2, gb2, mind, maxd, sde, bsb);

  mfma_gemm<3><<<dim3(2, 256), 256, 0, stream>>>(bsb, inWt, in_b, bxb, 64, 128);

  for (int l = 0; l < 4; l++) {
    qkv_attn<<<BB * NHD, 256, 0, stream>>>(bxb, qkvWt + l * 49152,
                                           bq + l * DD, bk + l * DD, bv + l * DD,
                                           bob);
    gemm_ln<<<512, 256, 0, stream>>>(bob, Wot + l * 16384, bo + l * DD, bxb,
                                     ln1s + l * DD, ln1b + l * DD, bxb, 128);
    mfma_gemm<1><<<dim3(8, 256), 256, 0, stream>>>(bxb, fW1t + l * 65536,
                                                   fb1 + l * 512, bh, 128, 512);
    gemm_ln<<<512, 256, 0, stream>>>(bh, fW2t + l * 65536, fb2 + l * DD, bxb,
                                     ln2s + l * DD, ln2b + l * DD, bxb, 512);
  }

  pool_kernel<<<BB, 128, 0, stream>>>(bxb, bp);
  cls_kernel<<<BB, 64, 0, stream>>>(bp, cW1, cb1, cW2, cb2, logits);
}

// Round 11
// 1376.901 us; speedup vs baseline: 1.4129x; 1.4129x over previous
//
#include <hip/hip_runtime.h>
#include <hip/hip_bf16.h>
#include <math.h>

#define BB 64
#define SS 512
#define HH 64
#define DD 128
#define NHD 8
#define ROWS (BB*SS)   // 32768

typedef unsigned short u16;
typedef __attribute__((ext_vector_type(8))) short bf16x8;
typedef __attribute__((ext_vector_type(4))) float f32x4;

__device__ __forceinline__ u16 f2b(float f) {
  union { float f; unsigned u; } x; x.f = f;
  unsigned r = x.u + 0x7fffu + ((x.u >> 16) & 1u);
  return (u16)(r >> 16);
}

__device__ __forceinline__ float b2f(u16 u) {
  return __uint_as_float(((unsigned)u) << 16);
}

__device__ __forceinline__ float fast_tanh(float x) {
  float ax = fminf(fabsf(x), 15.f);
  float e = __expf(2.f * ax);
  float r = 1.f - __fdividef(2.f, e + 1.f);
  return copysignf(r, x);
}

__device__ __forceinline__ void barrier_lds() {
  __builtin_amdgcn_s_waitcnt(0xC07F);   // lgkmcnt(0) only
  __builtin_amdgcn_s_barrier();
}

// ---------------------------------------------------------------------------
// SDE scan (v6 — measured best at 583 us; declared structural floor).
// 512 thr, stage A 2-way split, B 4-way, C 8-way, LDS-only barriers.
// ---------------------------------------------------------------------------
__global__ __launch_bounds__(512, 2) void sde_kernel(
    const float* __restrict__ ts, const float* __restrict__ noise,
    const float* __restrict__ dW1, const float* __restrict__ db1,
    const float* __restrict__ dW2, const float* __restrict__ db2,
    const float* __restrict__ dW3, const float* __restrict__ db3,
    const float* __restrict__ gW1, const float* __restrict__ gb1,
    const float* __restrict__ gW2, const float* __restrict__ gb2,
    const float* __restrict__ pmind, const float* __restrict__ pmaxd,
    float* __restrict__ out, u16* __restrict__ outB) {
  const int b = blockIdx.x, t = threadIdx.x;
  __shared__ float y_s[64];
  __shared__ float h1g1[256];
  __shared__ float h2s[64], gcs[64];
  __shared__ float tl_s[512], hs_s[512], sq_s[512];

  const float mind = fabsf(pmind[0]);
  const float maxd = fabsf(pmaxd[0]);

  const int oA = t >> 1, hA = t & 1;
  const int cA = oA & 127;
  const float* W1 = (oA < 128) ? dW1 : gW1;
  float wA[32];
#pragma unroll
  for (int k = 0; k < 32; k++) wA[k] = W1[(hA * 32 + k) * 128 + cA];
  const float wAt = W1[64 * 128 + cA];
  const float bA = ((oA < 128) ? db1 : gb1)[cA];

  const int oB = t >> 2, qB = t & 3;
  const int cB = oB & 63;
  const float* W2 = (oB < 64) ? dW2 : gW2;
  float wB[32];
#pragma unroll
  for (int k = 0; k < 32; k++) wB[k] = W2[(qB * 32 + k) * 64 + cB];
  const float bB = ((oB < 64) ? db2 : gb2)[cB];

  const int cC = t >> 3, qC = t & 7;
  float wC[8];
#pragma unroll
  for (int k = 0; k < 8; k++) wC[k] = dW3[(qC * 8 + k) * 64 + cC];
  const float bC = db3[cC];

  // prologue
  tl_s[t] = ts[t * 3];
  __syncthreads();
  if (t < 511) {
    float hh = tl_s[t + 1] - tl_s[t];
    hs_s[t] = hh;
    sq_s[t] = sqrtf(hh);
  }
  if (t < 64) {
    float y = 0.1f;
    if (t < 3) y = fminf(fmaxf(ts[b * 1536 + t], 0.01f), 10.f);
    y_s[t] = y;
    out[(long)b * 32768 + t] = y;
    outB[((long)b * 512) * 64 + t] = f2b(y);
  }
  float nz = noise[b * 64 + cC];
  __syncthreads();

  for (int i = 0; i < 511; i++) {
    float nzn = 0.f;
    if (i < 510) nzn = noise[(long)(i + 1) * 4096 + b * 64 + cC];
    const float tl = tl_s[i];
    const float hh = hs_s[i];
    const float sq = sq_s[i];

    // ---- stage A ----
    float a0 = 0.f, a1 = 0.f, a2 = 0.f, a3 = 0.f;
#pragma unroll
    for (int g = 0; g < 8; g++) {
      float4 yv = *(const float4*)&y_s[hA * 32 + g * 4];
      a0 += yv.x * wA[g * 4 + 0];
      a1 += yv.y * wA[g * 4 + 1];
      a2 += yv.z * wA[g * 4 + 2];
      a3 += yv.w * wA[g * 4 + 3];
    }
    float p1 = (a0 + a1) + (a2 + a3);
    if (hA == 0) p1 += tl * wAt + bA;
    p1 += __shfl_xor(p1, 1);
    if (hA == 0) h1g1[oA] = fast_tanh(p1);
    barrier_lds();                        // barrier 1

    // ---- stage B ----
    const float* srcB = h1g1 + ((oB < 64) ? 0 : 128) + qB * 32;
    float c0 = 0.f, c1 = 0.f, c2 = 0.f, c3 = 0.f;
#pragma unroll
    for (int g = 0; g < 8; g++) {
      float4 xv = *(const float4*)&srcB[g * 4];
      c0 += xv.x * wB[g * 4 + 0];
      c1 += xv.y * wB[g * 4 + 1];
      c2 += xv.z * wB[g * 4 + 2];
      c3 += xv.w * wB[g * 4 + 3];
    }
    float p2 = (c0 + c1) + (c2 + c3);
    p2 += __shfl_xor(p2, 1);
    p2 += __shfl_xor(p2, 2);
    if (qB == 0) {
      p2 += bB;
      if (oB < 64) {
        h2s[cB] = fast_tanh(p2);
      } else {
        gcs[cB] = fmaxf(p2, 0.f) + __logf(1.f + __expf(-fabsf(p2))) + mind;
      }
    }
    barrier_lds();                        // barrier 2

    // ---- stage C ----
    float d0 = 0.f, d1 = 0.f;
#pragma unroll
    for (int g = 0; g < 2; g++) {
      float4 hv = *(const float4*)&h2s[qC * 8 + g * 4];
      d0 += hv.x * wC[g * 4 + 0];
      d0 += hv.y * wC[g * 4 + 1];
      d1 += hv.z * wC[g * 4 + 2];
      d1 += hv.w * wC[g * 4 + 3];
    }
    float p3 = d0 + d1;
    p3 += __shfl_xor(p3, 1);
    p3 += __shfl_xor(p3, 2);
    p3 += __shfl_xor(p3, 4);
    if (qC == 0) {
      float dc = fminf(fmaxf(p3 + bC, -maxd), maxd);
      float yo = y_s[cC];
      float gg = gcs[cC] * fminf(fmaxf(yo, -10.f), 10.f);
      float yn = yo + dc * yo * hh + gg * nz * sq;
      yn = fminf(fmaxf(yn, 0.01f), 10.f);
      y_s[cC] = yn;
      out[(long)b * 32768 + (i + 1) * 64 + cC] = yn;
      outB[((long)b * 512 + i + 1) * 64 + cC] = f2b(yn);
    }
    nz = nzn;
    barrier_lds();                        // barrier 3
  }
}

// ---------------------------------------------------------------------------
__global__ __launch_bounds__(256) void prep_weights(
    const float* __restrict__ in_W, const float* __restrict__ Wq,
    const float* __restrict__ Wk, const float* __restrict__ Wv,
    const float* __restrict__ Wo, const float* __restrict__ fW1,
    const float* __restrict__ fW2,
    u16* __restrict__ inWt, u16* __restrict__ qkvWt, u16* __restrict__ Wot,
    u16* __restrict__ fW1t, u16* __restrict__ fW2t) {
  const int z = blockIdx.z, layer = blockIdx.y, tile = blockIdx.x;
  const float* src; u16* dst; int R, C, nl;
  switch (z) {
    case 0: src = in_W; dst = inWt; R = 64; C = 128; nl = 1; break;
    case 1: src = Wq + layer * 16384; dst = qkvWt + layer * 49152; R = 128; C = 128; nl = 4; break;
    case 2: src = Wk + layer * 16384; dst = qkvWt + layer * 49152 + 16384; R = 128; C = 128; nl = 4; break;
    case 3: src = Wv + layer * 16384; dst = qkvWt + layer * 49152 + 32768; R = 128; C = 128; nl = 4; break;
    case 4: src = Wo + layer * 16384; dst = Wot + layer * 16384; R = 128; C = 128; nl = 4; break;
    case 5: src = fW1 + layer * 65536; dst = fW1t + layer * 65536; R = 128; C = 512; nl = 4; break;
    default: src = fW2 + layer * 65536; dst = fW2t + layer * 65536; R = 512; C = 128; nl = 4; break;
  }
  const int nt = (R / 32) * (C / 32);
  if (layer >= nl || tile >= nt) return;
  const int tpr = C / 32;
  const int r0 = (tile / tpr) * 32, c0 = (tile % tpr) * 32;
  __shared__ float tl[32][33];
  const int tx = threadIdx.x & 31, ty = threadIdx.x >> 5;
#pragma unroll
  for (int p = 0; p < 4; p++)
    tl[ty + 8 * p][tx] = src[(long)(r0 + ty + 8 * p) * C + c0 + tx];
  __syncthreads();
#pragma unroll
  for (int p = 0; p < 4; p++)
    dst[(long)(c0 + ty + 8 * p) * R + r0 + tx] = f2b(tl[tx][ty + 8 * p]);
}

// ---------------------------------------------------------------------------
// bf16 MFMA GEMM (input projection). MODE 3: bf16 out.
// ---------------------------------------------------------------------------
template <int MODE>
__global__ __launch_bounds__(256) void mfma_gemm(
    const u16* __restrict__ A, const u16* __restrict__ Bt,
    const float* __restrict__ bias, u16* __restrict__ outB, int K, int N) {
  __shared__ u16 As[128 * 40];
  __shared__ u16 Bs[64 * 40];
  const int t = threadIdx.x;
  const int nb = blockIdx.x * 64;
  const long mb = (long)blockIdx.y * 128;
  const int lane = t & 63, wave = t >> 6;
  const int wm = (wave >> 1) * 64, wn = (wave & 1) * 32;
  const int fr = lane & 15, quad = lane >> 4;

  f32x4 zero = {0.f, 0.f, 0.f, 0.f};
  f32x4 acc[4][2];
#pragma unroll
  for (int mi = 0; mi < 4; mi++)
#pragma unroll
    for (int ni = 0; ni < 2; ni++) acc[mi][ni] = zero;

  for (int k0 = 0; k0 < K; k0 += 32) {
#pragma unroll
    for (int p = 0; p < 2; p++) {
      int idx = t + p * 256, row = idx >> 2, seg = idx & 3;
      int4 v = *(const int4*)&A[(mb + row) * K + k0 + seg * 8];
      *(int4*)&As[row * 40 + seg * 8] = v;
    }
    {
      int row = t >> 2, seg = t & 3;
      int4 v = *(const int4*)&Bt[(long)(nb + row) * K + k0 + seg * 8];
      *(int4*)&Bs[row * 40 + seg * 8] = v;
    }
    __syncthreads();
    bf16x8 af[4], bfr[2];
#pragma unroll
    for (int mi = 0; mi < 4; mi++)
      af[mi] = *(const bf16x8*)&As[(wm + mi * 16 + fr) * 40 + quad * 8];
#pragma unroll
    for (int ni = 0; ni < 2; ni++)
      bfr[ni] = *(const bf16x8*)&Bs[(wn + ni * 16 + fr) * 40 + quad * 8];
#pragma unroll
    for (int mi = 0; mi < 4; mi++)
#pragma unroll
      for (int ni = 0; ni < 2; ni++)
        acc[mi][ni] = __builtin_amdgcn_mfma_f32_16x16x32_bf16(
            af[mi], bfr[ni], acc[mi][ni], 0, 0, 0);
    __syncthreads();
  }

#pragma unroll
  for (int mi = 0; mi < 4; mi++)
#pragma unroll
    for (int ni = 0; ni < 2; ni++) {
      int col = nb + wn + ni * 16 + fr;
      float bv = bias[col];
#pragma unroll
      for (int r = 0; r < 4; r++) {
        long row = mb + wm + mi * 16 + quad * 4 + r;
        float v = acc[mi][ni][r] + bv;
        if (MODE == 1) {
          outB[row * N + col] = f2b(fmaxf(v, 0.f));
        } else {
          outB[row * N + col] = f2b(v);
        }
      }
    }
}

// ---------------------------------------------------------------------------
// Fused GEMM + residual(bf16) + LayerNorm -> bf16. Tile 64x128, 512 blocks.
// (O-projection)
// ---------------------------------------------------------------------------
__global__ __launch_bounds__(256) void gemm_ln(
    const u16* __restrict__ A, const u16* __restrict__ Bt,
    const float* __restrict__ bias, const u16* __restrict__ resid,
    const float* __restrict__ gamma, const float* __restrict__ beta,
    u16* __restrict__ outB, int K) {
  __shared__ u16 As[64 * 40];
  __shared__ u16 Bs[128 * 40];
  __shared__ float s1[2][64], s2[2][64];
  const int t = threadIdx.x;
  const long mb = (long)blockIdx.x * 64;
  const int lane = t & 63, wave = t >> 6;
  const int wm = (wave >> 1) * 32, wn = (wave & 1) * 64;
  const int fr = lane & 15, quad = lane >> 4;

  f32x4 zero = {0.f, 0.f, 0.f, 0.f};
  f32x4 acc[2][4];
#pragma unroll
  for (int mi = 0; mi < 2; mi++)
#pragma unroll
    for (int ni = 0; ni < 4; ni++) acc[mi][ni] = zero;

  for (int k0 = 0; k0 < K; k0 += 32) {
    {
      int row = t >> 2, seg = t & 3;
      *(int4*)&As[row * 40 + seg * 8] =
          *(const int4*)&A[(mb + row) * K + k0 + seg * 8];
    }
#pragma unroll
    for (int p = 0; p < 2; p++) {
      int idx = t + p * 256, row = idx >> 2, seg = idx & 3;
      *(int4*)&Bs[row * 40 + seg * 8] =
          *(const int4*)&Bt[(long)row * K + k0 + seg * 8];
    }
    __syncthreads();
    bf16x8 af[2], bfr[4];
#pragma unroll
    for (int mi = 0; mi < 2; mi++)
      af[mi] = *(const bf16x8*)&As[(wm + mi * 16 + fr) * 40 + quad * 8];
#pragma unroll
    for (int ni = 0; ni < 4; ni++)
      bfr[ni] = *(const bf16x8*)&Bs[(wn + ni * 16 + fr) * 40 + quad * 8];
#pragma unroll
    for (int mi = 0; mi < 2; mi++)
#pragma unroll
      for (int ni = 0; ni < 4; ni++)
        acc[mi][ni] = __builtin_amdgcn_mfma_f32_16x16x32_bf16(
            af[mi], bfr[ni], acc[mi][ni], 0, 0, 0);
    __syncthreads();
  }

  float bv[4], gv[4], be[4];
#pragma unroll
  for (int ni = 0; ni < 4; ni++) {
    int col = wn + ni * 16 + fr;
    bv[ni] = bias[col];
    gv[ni] = gamma[col];
    be[ni] = beta[col];
  }

#pragma unroll
  for (int mi = 0; mi < 2; mi++) {
#pragma unroll
    for (int r = 0; r < 4; r++) {
      int rloc = wm + mi * 16 + quad * 4 + r;
      long row = mb + rloc;
      float s = 0.f, ss = 0.f;
#pragma unroll
      for (int ni = 0; ni < 4; ni++) {
        int col = wn + ni * 16 + fr;
        float v = acc[mi][ni][r] + bv[ni] + b2f(resid[row * DD + col]);
        acc[mi][ni][r] = v;
        s += v;
        ss += v * v;
      }
      s += __shfl_xor(s, 1); ss += __shfl_xor(ss, 1);
      s += __shfl_xor(s, 2); ss += __shfl_xor(ss, 2);
      s += __shfl_xor(s, 4); ss += __shfl_xor(ss, 4);
      s += __shfl_xor(s, 8); ss += __shfl_xor(ss, 8);
      if (fr == 0) {
        s1[wn >> 6][rloc] = s;
        s2[wn >> 6][rloc] = ss;
      }
    }
  }
  __syncthreads();

#pragma unroll
  for (int mi = 0; mi < 2; mi++) {
#pragma unroll
    for (int r = 0; r < 4; r++) {
      int rloc = wm + mi * 16 + quad * 4 + r;
      long row = mb + rloc;
      float sum = s1[0][rloc] + s1[1][rloc];
      float sumsq = s2[0][rloc] + s2[1][rloc];
      float mean = sum * (1.f / 128.f);
      float var = sumsq * (1.f / 128.f) - mean * mean;
      float rstd = rsqrtf(var + 1e-5f);
#pragma unroll
      for (int ni = 0; ni < 4; ni++) {
        int col = wn + ni * 16 + fr;
        float o = (acc[mi][ni][r] - mean) * rstd * gv[ni] + be[ni];
        outB[row * DD + col] = f2b(o);
      }
    }
  }
}

// ---------------------------------------------------------------------------
// Fused FFN: out = LN(x + relu(x@W1+b1)@W2+b2). 32-row tile, 1024 blocks.
// Hidden kept in 32 KB LDS with XOR swizzle (chunk^(row&7)) so phase-2
// b128 A-frag reads are 2-way banked (free). In-place on x (resid reads
// precede stores; cross-wave ordering via the two barriers).
// ---------------------------------------------------------------------------
__global__ __launch_bounds__(256) void ffn_fused(
    const u16* __restrict__ xb, const u16* __restrict__ fW1t,
    const float* __restrict__ fb1, const u16* __restrict__ fW2t,
    const float* __restrict__ fb2, const float* __restrict__ gamma,
    const float* __restrict__ beta, u16* __restrict__ outB) {
  __shared__ u16 hT[32 * 512];             // [row][k], XOR-swizzled chunks
  __shared__ float s1[2][32], s2[2][32];
  const int t = threadIdx.x;
  const long mb = (long)blockIdx.x * 32;
  const int lane = t & 63, w = t >> 6;
  const int fr = lane & 15, quad = lane >> 4;
  const int mtile = w & 1, nhalf = w >> 1;
  const f32x4 z4 = {0.f, 0.f, 0.f, 0.f};

  // x A-frags for this wave's 16 rows (reused for all 32 hidden n-tiles)
  bf16x8 af[4];
#pragma unroll
  for (int c = 0; c < 4; c++)
    af[c] = *(const bf16x8*)&xb[(mb + mtile * 16 + fr) * DD + c * 32 + quad * 8];

  // ---- phase 1: hidden = relu(x @ W1 + b1) -> LDS ----
  for (int nt = 0; nt < 16; nt++) {
    const int col0 = nhalf * 256 + nt * 16;
    f32x4 acc = z4;
#pragma unroll
    for (int c = 0; c < 4; c++) {
      bf16x8 bf = *(const bf16x8*)&fW1t[(long)(col0 + fr) * DD + c * 32 + quad * 8];
      acc = __builtin_amdgcn_mfma_f32_16x16x32_bf16(af[c], bf, acc, 0, 0, 0);
    }
    const float bb = fb1[col0 + fr];
    const int chunkBase = (col0 + fr) >> 3;   // logical 8-elem chunk
    const int sub = fr & 7;
#pragma unroll
    for (int r = 0; r < 4; r++) {
      int row = mtile * 16 + quad * 4 + r;
      int phys = chunkBase ^ (row & 7);
      hT[row * 512 + phys * 8 + sub] = f2b(fmaxf(acc[r] + bb, 0.f));
    }
  }
  __syncthreads();

  // ---- phase 2: out = hidden @ W2 + b2 + resid, then LN ----
  f32x4 acc2[4];
#pragma unroll
  for (int n = 0; n < 4; n++) acc2[n] = z4;
  const int rowA = mtile * 16 + fr;
  for (int kc = 0; kc < 16; kc++) {
    int physA = (kc * 4 + quad) ^ (fr & 7);
    bf16x8 af2 = *(const bf16x8*)&hT[rowA * 512 + physA * 8];
#pragma unroll
    for (int n = 0; n < 4; n++) {
      int col = nhalf * 64 + n * 16 + fr;
      bf16x8 bf2 = *(const bf16x8*)&fW2t[(long)col * 512 + kc * 32 + quad * 8];
      acc2[n] = __builtin_amdgcn_mfma_f32_16x16x32_bf16(af2, bf2, acc2[n], 0, 0, 0);
    }
  }

  float bv[4], gv[4], be[4];
#pragma unroll
  for (int n = 0; n < 4; n++) {
    int col = nhalf * 64 + n * 16 + fr;
    bv[n] = fb2[col];
    gv[n] = gamma[col];
    be[n] = beta[col];
  }

  float vres[4][4];
#pragma unroll
  for (int r = 0; r < 4; r++) {
    int rloc = mtile * 16 + quad * 4 + r;
    long row = mb + rloc;
    float s = 0.f, ss = 0.f;
#pragma unroll
    for (int n = 0; n < 4; n++) {
      int col = nhalf * 64 + n * 16 + fr;
      float v = acc2[n][r] + bv[n] + b2f(xb[row * DD + col]);
      vres[r][n] = v;
      s += v;
      ss += v * v;
    }
    s += __shfl_xor(s, 1); ss += __shfl_xor(ss, 1);
    s += __shfl_xor(s, 2); ss += __shfl_xor(ss, 2);
    s += __shfl_xor(s, 4); ss += __shfl_xor(ss, 4);
    s += __shfl_xor(s, 8); ss += __shfl_xor(ss, 8);
    if (fr == 0) {
      s1[nhalf][rloc] = s;
      s2[nhalf][rloc] = ss;
    }
  }
  __syncthreads();

#pragma unroll
  for (int r = 0; r < 4; r++) {
    int rloc = mtile * 16 + quad * 4 + r;
    long row = mb + rloc;
    float sum = s1[0][rloc] + s1[1][rloc];
    float sumsq = s2[0][rloc] + s2[1][rloc];
    float mean = sum * (1.f / 128.f);
    float var = sumsq * (1.f / 128.f) - mean * mean;
    float rstd = rsqrtf(var + 1e-5f);
#pragma unroll
    for (int n = 0; n < 4; n++) {
      int col = nhalf * 64 + n * 16 + fr;
      float o = (vres[r][n] - mean) * rstd * gv[n] + be[n];
      outB[row * DD + col] = f2b(o);
    }
  }
}

// ---------------------------------------------------------------------------
// Fused QKV-projection + flash attention (verified round 9).
// ---------------------------------------------------------------------------
__global__ __launch_bounds__(256, 2) void qkv_attn(
    const u16* __restrict__ xb, const u16* __restrict__ qkvW,
    const float* __restrict__ bq, const float* __restrict__ bk,
    const float* __restrict__ bv, u16* __restrict__ Og) {
  const int bh = blockIdx.x;
  const int b = bh >> 3, h = bh & 7;
  __shared__ u16 Ks[512 * 24];
  __shared__ u16 Vt[16 * 520];
  __shared__ u16 Qs[512 * 24];
  const int t = threadIdx.x;
  const int w = t >> 6, lane = t & 63;
  const int fr = lane & 15, quad = lane >> 4;
  const long obase = ((long)b * SS) * DD + h * 16;
  const u16* xrow = xb + (long)b * SS * DD;

  const u16* Wq_h = qkvW + (h * 16) * 128;
  const u16* Wk_h = qkvW + 16384 + (h * 16) * 128;
  const u16* Wv_h = qkvW + 32768 + (h * 16) * 128;
  bf16x8 wqf[4], wkf[4], wvf[4];
#pragma unroll
  for (int c = 0; c < 4; c++) {
    wqf[c] = *(const bf16x8*)&Wq_h[fr * 128 + c * 32 + quad * 8];
    wkf[c] = *(const bf16x8*)&Wk_h[fr * 128 + c * 32 + quad * 8];
    wvf[c] = *(const bf16x8*)&Wv_h[fr * 128 + c * 32 + quad * 8];
  }
  const float bqv = bq[h * 16 + fr];
  const float bkv = bk[h * 16 + fr];
  const float bvv = bv[h * 16 + fr];
  const f32x4 z4 = {0.f, 0.f, 0.f, 0.f};

  for (int tile = w; tile < 32; tile += 4) {
    const int t0 = tile * 16;
    bf16x8 af[4];
#pragma unroll
    for (int c = 0; c < 4; c++)
      af[c] = *(const bf16x8*)&xrow[(t0 + fr) * 128 + c * 32 + quad * 8];
    f32x4 qa = z4, ka = z4, va = z4;
#pragma unroll
    for (int c = 0; c < 4; c++) {
      qa = __builtin_amdgcn_mfma_f32_16x16x32_bf16(af[c], wqf[c], qa, 0, 0, 0);
      ka = __builtin_amdgcn_mfma_f32_16x16x32_bf16(af[c], wkf[c], ka, 0, 0, 0);
      va = __builtin_amdgcn_mfma_f32_16x16x32_bf16(af[c], wvf[c], va, 0, 0, 0);
    }
#pragma unroll
    for (int r = 0; r < 4; r++) {
      int row = t0 + quad * 4 + r;
      Qs[row * 24 + fr] = f2b(qa[r] + bqv);
      Ks[row * 24 + fr] = f2b(ka[r] + bkv);
      Vt[fr * 520 + row] = f2b(va[r] + bvv);
    }
  }
  __syncthreads();

  const float scale = 0.25f;
  const int addrA = (((quad & 1) * 32) + fr) * 4;
  const int addrB = addrA + 64;
  const bool loTile = (quad < 2);

  for (int qt = w; qt < 32; qt += 4) {
    const int q0 = qt * 16;
    bf16x8 qf = {0, 0, 0, 0, 0, 0, 0, 0};
    if (quad < 2)
      qf = *(const bf16x8*)&Qs[(q0 + fr) * 24 + quad * 8];
    f32x4 oacc = {0.f, 0.f, 0.f, 0.f};
    float mrun = -1e30f, lrun = 0.f;

    for (int kt = 0; kt < 16; kt++) {
      const int k0 = kt * 32;
      bf16x8 kf0 = {0, 0, 0, 0, 0, 0, 0, 0};
      bf16x8 kf1 = {0, 0, 0, 0, 0, 0, 0, 0};
      if (quad < 2) {
        kf0 = *(const bf16x8*)&Ks[(k0 + fr) * 24 + quad * 8];
        kf1 = *(const bf16x8*)&Ks[(k0 + 16 + fr) * 24 + quad * 8];
      }
      f32x4 slo = __builtin_amdgcn_mfma_f32_16x16x32_bf16(kf0, qf, z4, 0, 0, 0);
      f32x4 shi = __builtin_amdgcn_mfma_f32_16x16x32_bf16(kf1, qf, z4, 0, 0, 0);
      float s[8];
#pragma unroll
      for (int r = 0; r < 4; r++) {
        s[r] = slo[r] * scale;
        s[4 + r] = shi[r] * scale;
      }
      float mx = s[0];
#pragma unroll
      for (int r = 1; r < 8; r++) mx = fmaxf(mx, s[r]);
      mx = fmaxf(mx, __shfl_xor(mx, 16));
      mx = fmaxf(mx, __shfl_xor(mx, 32));
      float nm = fmaxf(mrun, mx);
      float alpha = __expf(mrun - nm);
      mrun = nm;
      float p[8], rs = 0.f;
#pragma unroll
      for (int r = 0; r < 8; r++) {
        p[r] = __expf(s[r] - nm);
        rs += p[r];
      }
      rs += __shfl_xor(rs, 16);
      rs += __shfl_xor(rs, 32);
      lrun = lrun * alpha + rs;
#pragma unroll
      for (int r = 0; r < 4; r++) oacc[r] *= alpha;

      int pk0 = ((int)f2b(p[1]) << 16) | f2b(p[0]);
      int pk1 = ((int)f2b(p[3]) << 16) | f2b(p[2]);
      int pk2 = ((int)f2b(p[5]) << 16) | f2b(p[4]);
      int pk3 = ((int)f2b(p[7]) << 16) | f2b(p[6]);
      int B0a = __builtin_amdgcn_ds_bpermute(addrA, pk0);
      int B0b = __builtin_amdgcn_ds_bpermute(addrA, pk2);
      int B1a = __builtin_amdgcn_ds_bpermute(addrA, pk1);
      int B1b = __builtin_amdgcn_ds_bpermute(addrA, pk3);
      int B2a = __builtin_amdgcn_ds_bpermute(addrB, pk0);
      int B2b = __builtin_amdgcn_ds_bpermute(addrB, pk2);
      int B3a = __builtin_amdgcn_ds_bpermute(addrB, pk1);
      int B3b = __builtin_amdgcn_ds_bpermute(addrB, pk3);
      union { int i[4]; bf16x8 v; } pu;
      pu.i[0] = loTile ? B0a : B0b;
      pu.i[1] = loTile ? B1a : B1b;
      pu.i[2] = loTile ? B2a : B2b;
      pu.i[3] = loTile ? B3a : B3b;
      bf16x8 vf = *(const bf16x8*)&Vt[fr * 520 + k0 + quad * 8];
      oacc = __builtin_amdgcn_mfma_f32_16x16x32_bf16(vf, pu.v, oacc, 0, 0, 0);
    }

    float inv = __fdividef(1.f, lrun);
    ushort4 o;
    o.x = f2b(oacc[0] * inv);
    o.y = f2b(oacc[1] * inv);
    o.z = f2b(oacc[2] * inv);
    o.w = f2b(oacc[3] * inv);
    *(ushort4*)&Og[obase + (long)(q0 + fr) * DD + quad * 4] = o;
  }
}

// ---------------------------------------------------------------------------
// Fused mean-pool + classifier.
// ---------------------------------------------------------------------------
__global__ __launch_bounds__(128) void pool_cls(
    const u16* __restrict__ X, const float* __restrict__ W1,
    const float* __restrict__ b1, const float* __restrict__ W2,
    const float* __restrict__ b2, float* __restrict__ L) {
  const int b = blockIdx.x, t = threadIdx.x;
  __shared__ float sp[128];
  __shared__ float sh[64];
  float acc = 0.f;
  for (int s = 0; s < SS; s++) acc += b2f(X[((long)b * SS + s) * DD + t]);
  sp[t] = acc * (1.f / 512.f);
  __syncthreads();
  if (t < 64) {
    float a = b1[t];
    for (int k = 0; k < 128; k++) a += sp[k] * W1[k * 64 + t];
    sh[t] = fmaxf(a, 0.f);
  }
  __syncthreads();
  if (t < 5) {
    float a2 = b2[t];
    for (int k = 0; k < 64; k++) a2 += sh[k] * W2[k * 5 + t];
    L[b * 5 + t] = a2;
  }
}

// ---------------------------------------------------------------------------
extern "C" void kernel_launch(void* const* d_in, const int* in_sizes, int n_in,
                              void* d_out, int out_size, void* d_ws, size_t ws_size,
                              hipStream_t stream) {
  const float* ts    = (const float*)d_in[0];
  const float* noise = (const float*)d_in[2];
  const float* dW1   = (const float*)d_in[3];
  const float* db1   = (const float*)d_in[4];
  const float* dW2   = (const float*)d_in[5];
  const float* db2   = (const float*)d_in[6];
  const float* dW3   = (const float*)d_in[7];
  const float* db3   = (const float*)d_in[8];
  const float* gW1   = (const float*)d_in[9];
  const float* gb1   = (const float*)d_in[10];
  const float* gW2   = (const float*)d_in[11];
  const float* gb2   = (const float*)d_in[12];
  const float* mind  = (const float*)d_in[13];
  const float* maxd  = (const float*)d_in[14];
  const float* in_W  = (const float*)d_in[15];
  const float* in_b  = (const float*)d_in[16];
  const float* Wq    = (const float*)d_in[17];
  const float* bq    = (const float*)d_in[18];
  const float* Wk    = (const float*)d_in[19];
  const float* bk    = (const float*)d_in[20];
  const float* Wv    = (const float*)d_in[21];
  const float* bv    = (const float*)d_in[22];
  const float* Wo    = (const float*)d_in[23];
  const float* bo    = (const float*)d_in[24];
  const float* ln1s  = (const float*)d_in[25];
  const float* ln1b  = (const float*)d_in[26];
  const float* fW1   = (const float*)d_in[27];
  const float* fb1   = (const float*)d_in[28];
  const float* fW2   = (const float*)d_in[29];
  const float* fb2   = (const float*)d_in[30];
  const float* ln2s  = (const float*)d_in[31];
  const float* ln2b  = (const float*)d_in[32];
  const float* cW1   = (const float*)d_in[33];
  const float* cb1   = (const float*)d_in[34];
  const float* cW2   = (const float*)d_in[35];
  const float* cb2   = (const float*)d_in[36];

  float* logits = (float*)d_out;
  float* sde    = logits + BB * 5;

  char* W = (char*)d_ws;
  u16*  bxb    = (u16*)(W);                   //  8 MB bf16 x (residual stream)
  u16*  bob    = (u16*)(W + (8u << 20));      //  8 MB bf16 attn out
  u16*  bsb    = (u16*)(W + (16u << 20));     //  4 MB bf16 sde feats
  u16*  wts    = (u16*)(W + (20u << 20));     // ~1.5 MB bf16 weights
  float* bp    = (float*)(W + (22u << 20));   // scratch

  u16* inWt  = wts;                 // [128][64]
  u16* qkvWt = inWt + 8192;         // [4][3][128][128]
  u16* Wot   = qkvWt + 196608;      // [4][128][128]
  u16* fW1t  = Wot + 65536;         // [4][512][128]
  u16* fW2t  = fW1t + 262144;       // [4][128][512]

  prep_weights<<<dim3(64, 4, 7), 256, 0, stream>>>(in_W, Wq, Wk, Wv, Wo, fW1, fW2,
                                                   inWt, qkvWt, Wot, fW1t, fW2t);

  sde_kernel<<<64, 512, 0, stream>>>(ts, noise, dW1, db1, dW2, db2, dW3, db3,
                                     gW1, gb1, gW2, gb2, mind, maxd, sde, bsb);

  mfma_gemm<3><<<dim3(2, 256), 256, 0, stream>>>(bsb, inWt, in_b, bxb, 64, 128);

  for (int l = 0; l < 4; l++) {
    qkv_attn<<<BB * NHD, 256, 0, stream>>>(bxb, qkvWt + l * 49152,
                                           bq + l * DD, bk + l * DD, bv + l * DD,
                                           bob);
    gemm_ln<<<512, 256, 0, stream>>>(bob, Wot + l * 16384, bo + l * DD, bxb,
                                     ln1s + l * DD, ln1b + l * DD, bxb, 128);
    ffn_fused<<<1024, 256, 0, stream>>>(bxb, fW1t + l * 65536, fb1 + l * 512,
                                        fW2t + l * 65536, fb2 + l * DD,
                                        ln2s + l * DD, ln2b + l * DD, bxb);
  }

  pool_cls<<<BB, 128, 0, stream>>>(bxb, cW1, cb1, cW2, cb2, logits);
  (void)bp;
}

// Round 12
// 1331.070 us; speedup vs baseline: 1.4616x; 1.0344x over previous
//
#include <hip/hip_runtime.h>
#include <hip/hip_bf16.h>
#include <math.h>

#define BB 64
#define SS 512
#define HH 64
#define DD 128
#define NHD 8
#define ROWS (BB*SS)   // 32768

typedef unsigned short u16;
typedef __attribute__((ext_vector_type(8))) short bf16x8;
typedef __attribute__((ext_vector_type(4))) float f32x4;

__device__ __forceinline__ u16 f2b(float f) {
  union { float f; unsigned u; } x; x.f = f;
  unsigned r = x.u + 0x7fffu + ((x.u >> 16) & 1u);
  return (u16)(r >> 16);
}

__device__ __forceinline__ float b2f(u16 u) {
  return __uint_as_float(((unsigned)u) << 16);
}

__device__ __forceinline__ float fast_tanh(float x) {
  float ax = fminf(fabsf(x), 15.f);
  float e = __expf(2.f * ax);
  float r = 1.f - __fdividef(2.f, e + 1.f);
  return copysignf(r, x);
}

__device__ __forceinline__ void barrier_lds() {
  __builtin_amdgcn_s_waitcnt(0xC07F);   // lgkmcnt(0) only
  __builtin_amdgcn_s_barrier();
}

// ---------------------------------------------------------------------------
// SDE scan v9: 1024 threads (4 waves/SIMD — TLP was the only lever that ever
// moved this kernel: 256thr=677, 512thr=583). Finer k-splits:
// stage A 4-way (16 FMA + 2 shfl), B 8-way (16 FMA + 3 shfl),
// C 16-way (4 FMA + 4 shfl). Per-wave LDS ops ~13 vs v6's ~29.
// ---------------------------------------------------------------------------
__global__ __launch_bounds__(1024, 1) void sde_kernel(
    const float* __restrict__ ts, const float* __restrict__ noise,
    const float* __restrict__ dW1, const float* __restrict__ db1,
    const float* __restrict__ dW2, const float* __restrict__ db2,
    const float* __restrict__ dW3, const float* __restrict__ db3,
    const float* __restrict__ gW1, const float* __restrict__ gb1,
    const float* __restrict__ gW2, const float* __restrict__ gb2,
    const float* __restrict__ pmind, const float* __restrict__ pmaxd,
    float* __restrict__ out, u16* __restrict__ outB) {
  const int b = blockIdx.x, t = threadIdx.x;
  __shared__ float y_s[64];
  __shared__ float h1g1[256];
  __shared__ float h2s[64], gcs[64];
  __shared__ float tl_s[512], hs_s[512], sq_s[512];

  const float mind = fabsf(pmind[0]);
  const float maxd = fabsf(pmaxd[0]);

  // stage A: output oA (0..255), 4-way k-split qA
  const int oA = t >> 2, qA = t & 3;
  const int cA = oA & 127;
  const float* W1 = (oA < 128) ? dW1 : gW1;
  float wA[16];
#pragma unroll
  for (int k = 0; k < 16; k++) wA[k] = W1[(qA * 16 + k) * 128 + cA];
  const float wAt = W1[64 * 128 + cA];
  const float bA = ((oA < 128) ? db1 : gb1)[cA];

  // stage B: output oB (0..127), 8-way k-split qB
  const int oB = t >> 3, qB = t & 7;
  const int cB = oB & 63;
  const float* W2 = (oB < 64) ? dW2 : gW2;
  float wB[16];
#pragma unroll
  for (int k = 0; k < 16; k++) wB[k] = W2[(qB * 16 + k) * 64 + cB];
  const float bB = ((oB < 64) ? db2 : gb2)[cB];

  // stage C: output cC (0..63), 16-way k-split qC
  const int cC = t >> 4, qC = t & 15;
  float wC[4];
#pragma unroll
  for (int k = 0; k < 4; k++) wC[k] = dW3[(qC * 4 + k) * 64 + cC];
  const float bC = db3[cC];

  // prologue
  if (t < 512) tl_s[t] = ts[t * 3];
  __syncthreads();
  if (t < 511) {
    float hh = tl_s[t + 1] - tl_s[t];
    hs_s[t] = hh;
    sq_s[t] = sqrtf(hh);
  }
  if (t < 64) {
    float y = 0.1f;
    if (t < 3) y = fminf(fmaxf(ts[b * 1536 + t], 0.01f), 10.f);
    y_s[t] = y;
    out[(long)b * 32768 + t] = y;
    outB[((long)b * 512) * 64 + t] = f2b(y);
  }
  float nz = noise[b * 64 + cC];
  __syncthreads();

  for (int i = 0; i < 511; i++) {
    float nzn = 0.f;
    if (i < 510) nzn = noise[(long)(i + 1) * 4096 + b * 64 + cC];
    const float tl = tl_s[i];
    const float hh = hs_s[i];
    const float sq = sq_s[i];

    // ---- stage A: 16 FMA + 2 shfl ----
    float a0 = 0.f, a1 = 0.f, a2 = 0.f, a3 = 0.f;
#pragma unroll
    for (int g = 0; g < 4; g++) {
      float4 yv = *(const float4*)&y_s[qA * 16 + g * 4];
      a0 += yv.x * wA[g * 4 + 0];
      a1 += yv.y * wA[g * 4 + 1];
      a2 += yv.z * wA[g * 4 + 2];
      a3 += yv.w * wA[g * 4 + 3];
    }
    float p1 = (a0 + a1) + (a2 + a3);
    if (qA == 0) p1 += tl * wAt + bA;
    p1 += __shfl_xor(p1, 1);
    p1 += __shfl_xor(p1, 2);
    if (qA == 0) h1g1[oA] = fast_tanh(p1);
    barrier_lds();                        // barrier 1

    // ---- stage B: 16 FMA + 3 shfl ----
    const float* srcB = h1g1 + ((oB < 64) ? 0 : 128) + qB * 16;
    float c0 = 0.f, c1 = 0.f, c2 = 0.f, c3 = 0.f;
#pragma unroll
    for (int g = 0; g < 4; g++) {
      float4 xv = *(const float4*)&srcB[g * 4];
      c0 += xv.x * wB[g * 4 + 0];
      c1 += xv.y * wB[g * 4 + 1];
      c2 += xv.z * wB[g * 4 + 2];
      c3 += xv.w * wB[g * 4 + 3];
    }
    float p2 = (c0 + c1) + (c2 + c3);
    p2 += __shfl_xor(p2, 1);
    p2 += __shfl_xor(p2, 2);
    p2 += __shfl_xor(p2, 4);
    if (qB == 0) {
      p2 += bB;
      if (oB < 64) {
        h2s[cB] = fast_tanh(p2);
      } else {
        gcs[cB] = fmaxf(p2, 0.f) + __logf(1.f + __expf(-fabsf(p2))) + mind;
      }
    }
    barrier_lds();                        // barrier 2

    // ---- stage C: 4 FMA + 4 shfl + update ----
    float4 hv = *(const float4*)&h2s[qC * 4];
    float p3 = hv.x * wC[0] + hv.y * wC[1] + hv.z * wC[2] + hv.w * wC[3];
    p3 += __shfl_xor(p3, 1);
    p3 += __shfl_xor(p3, 2);
    p3 += __shfl_xor(p3, 4);
    p3 += __shfl_xor(p3, 8);
    if (qC == 0) {
      float dc = fminf(fmaxf(p3 + bC, -maxd), maxd);
      float yo = y_s[cC];
      float gg = gcs[cC] * fminf(fmaxf(yo, -10.f), 10.f);
      float yn = yo + dc * yo * hh + gg * nz * sq;
      yn = fminf(fmaxf(yn, 0.01f), 10.f);
      y_s[cC] = yn;
      out[(long)b * 32768 + (i + 1) * 64 + cC] = yn;
      outB[((long)b * 512 + i + 1) * 64 + cC] = f2b(yn);
    }
    nz = nzn;
    barrier_lds();                        // barrier 3
  }
}

// ---------------------------------------------------------------------------
__global__ __launch_bounds__(256) void prep_weights(
    const float* __restrict__ in_W, const float* __restrict__ Wq,
    const float* __restrict__ Wk, const float* __restrict__ Wv,
    const float* __restrict__ Wo, const float* __restrict__ fW1,
    const float* __restrict__ fW2,
    u16* __restrict__ inWt, u16* __restrict__ qkvWt, u16* __restrict__ Wot,
    u16* __restrict__ fW1t, u16* __restrict__ fW2t) {
  const int z = blockIdx.z, layer = blockIdx.y, tile = blockIdx.x;
  const float* src; u16* dst; int R, C, nl;
  switch (z) {
    case 0: src = in_W; dst = inWt; R = 64; C = 128; nl = 1; break;
    case 1: src = Wq + layer * 16384; dst = qkvWt + layer * 49152; R = 128; C = 128; nl = 4; break;
    case 2: src = Wk + layer * 16384; dst = qkvWt + layer * 49152 + 16384; R = 128; C = 128; nl = 4; break;
    case 3: src = Wv + layer * 16384; dst = qkvWt + layer * 49152 + 32768; R = 128; C = 128; nl = 4; break;
    case 4: src = Wo + layer * 16384; dst = Wot + layer * 16384; R = 128; C = 128; nl = 4; break;
    case 5: src = fW1 + layer * 65536; dst = fW1t + layer * 65536; R = 128; C = 512; nl = 4; break;
    default: src = fW2 + layer * 65536; dst = fW2t + layer * 65536; R = 512; C = 128; nl = 4; break;
  }
  const int nt = (R / 32) * (C / 32);
  if (layer >= nl || tile >= nt) return;
  const int tpr = C / 32;
  const int r0 = (tile / tpr) * 32, c0 = (tile % tpr) * 32;
  __shared__ float tl[32][33];
  const int tx = threadIdx.x & 31, ty = threadIdx.x >> 5;
#pragma unroll
  for (int p = 0; p < 4; p++)
    tl[ty + 8 * p][tx] = src[(long)(r0 + ty + 8 * p) * C + c0 + tx];
  __syncthreads();
#pragma unroll
  for (int p = 0; p < 4; p++)
    dst[(long)(c0 + ty + 8 * p) * R + r0 + tx] = f2b(tl[tx][ty + 8 * p]);
}

// ---------------------------------------------------------------------------
// bf16 MFMA GEMM. MODE 1: bf16+relu. MODE 3: bf16.
// ---------------------------------------------------------------------------
template <int MODE>
__global__ __launch_bounds__(256) void mfma_gemm(
    const u16* __restrict__ A, const u16* __restrict__ Bt,
    const float* __restrict__ bias, u16* __restrict__ outB, int K, int N) {
  __shared__ u16 As[128 * 40];
  __shared__ u16 Bs[64 * 40];
  const int t = threadIdx.x;
  const int nb = blockIdx.x * 64;
  const long mb = (long)blockIdx.y * 128;
  const int lane = t & 63, wave = t >> 6;
  const int wm = (wave >> 1) * 64, wn = (wave & 1) * 32;
  const int fr = lane & 15, quad = lane >> 4;

  f32x4 zero = {0.f, 0.f, 0.f, 0.f};
  f32x4 acc[4][2];
#pragma unroll
  for (int mi = 0; mi < 4; mi++)
#pragma unroll
    for (int ni = 0; ni < 2; ni++) acc[mi][ni] = zero;

  for (int k0 = 0; k0 < K; k0 += 32) {
#pragma unroll
    for (int p = 0; p < 2; p++) {
      int idx = t + p * 256, row = idx >> 2, seg = idx & 3;
      int4 v = *(const int4*)&A[(mb + row) * K + k0 + seg * 8];
      *(int4*)&As[row * 40 + seg * 8] = v;
    }
    {
      int row = t >> 2, seg = t & 3;
      int4 v = *(const int4*)&Bt[(long)(nb + row) * K + k0 + seg * 8];
      *(int4*)&Bs[row * 40 + seg * 8] = v;
    }
    __syncthreads();
    bf16x8 af[4], bfr[2];
#pragma unroll
    for (int mi = 0; mi < 4; mi++)
      af[mi] = *(const bf16x8*)&As[(wm + mi * 16 + fr) * 40 + quad * 8];
#pragma unroll
    for (int ni = 0; ni < 2; ni++)
      bfr[ni] = *(const bf16x8*)&Bs[(wn + ni * 16 + fr) * 40 + quad * 8];
#pragma unroll
    for (int mi = 0; mi < 4; mi++)
#pragma unroll
      for (int ni = 0; ni < 2; ni++)
        acc[mi][ni] = __builtin_amdgcn_mfma_f32_16x16x32_bf16(
            af[mi], bfr[ni], acc[mi][ni], 0, 0, 0);
    __syncthreads();
  }

#pragma unroll
  for (int mi = 0; mi < 4; mi++)
#pragma unroll
    for (int ni = 0; ni < 2; ni++) {
      int col = nb + wn + ni * 16 + fr;
      float bv = bias[col];
#pragma unroll
      for (int r = 0; r < 4; r++) {
        long row = mb + wm + mi * 16 + quad * 4 + r;
        float v = acc[mi][ni][r] + bv;
        if (MODE == 1) {
          outB[row * N + col] = f2b(fmaxf(v, 0.f));
        } else {
          outB[row * N + col] = f2b(v);
        }
      }
    }
}

// ---------------------------------------------------------------------------
// Fused GEMM + residual(bf16) + LayerNorm -> bf16. Tile 64x128, 512 blocks.
// ---------------------------------------------------------------------------
__global__ __launch_bounds__(256) void gemm_ln(
    const u16* __restrict__ A, const u16* __restrict__ Bt,
    const float* __restrict__ bias, const u16* __restrict__ resid,
    const float* __restrict__ gamma, const float* __restrict__ beta,
    u16* __restrict__ outB, int K) {
  __shared__ u16 As[64 * 40];
  __shared__ u16 Bs[128 * 40];
  __shared__ float s1[2][64], s2[2][64];
  const int t = threadIdx.x;
  const long mb = (long)blockIdx.x * 64;
  const int lane = t & 63, wave = t >> 6;
  const int wm = (wave >> 1) * 32, wn = (wave & 1) * 64;
  const int fr = lane & 15, quad = lane >> 4;

  f32x4 zero = {0.f, 0.f, 0.f, 0.f};
  f32x4 acc[2][4];
#pragma unroll
  for (int mi = 0; mi < 2; mi++)
#pragma unroll
    for (int ni = 0; ni < 4; ni++) acc[mi][ni] = zero;

  for (int k0 = 0; k0 < K; k0 += 32) {
    {
      int row = t >> 2, seg = t & 3;
      *(int4*)&As[row * 40 + seg * 8] =
          *(const int4*)&A[(mb + row) * K + k0 + seg * 8];
    }
#pragma unroll
    for (int p = 0; p < 2; p++) {
      int idx = t + p * 256, row = idx >> 2, seg = idx & 3;
      *(int4*)&Bs[row * 40 + seg * 8] =
          *(const int4*)&Bt[(long)row * K + k0 + seg * 8];
    }
    __syncthreads();
    bf16x8 af[2], bfr[4];
#pragma unroll
    for (int mi = 0; mi < 2; mi++)
      af[mi] = *(const bf16x8*)&As[(wm + mi * 16 + fr) * 40 + quad * 8];
#pragma unroll
    for (int ni = 0; ni < 4; ni++)
      bfr[ni] = *(const bf16x8*)&Bs[(wn + ni * 16 + fr) * 40 + quad * 8];
#pragma unroll
    for (int mi = 0; mi < 2; mi++)
#pragma unroll
      for (int ni = 0; ni < 4; ni++)
        acc[mi][ni] = __builtin_amdgcn_mfma_f32_16x16x32_bf16(
            af[mi], bfr[ni], acc[mi][ni], 0, 0, 0);
    __syncthreads();
  }

  float bv[4], gv[4], be[4];
#pragma unroll
  for (int ni = 0; ni < 4; ni++) {
    int col = wn + ni * 16 + fr;
    bv[ni] = bias[col];
    gv[ni] = gamma[col];
    be[ni] = beta[col];
  }

#pragma unroll
  for (int mi = 0; mi < 2; mi++) {
#pragma unroll
    for (int r = 0; r < 4; r++) {
      int rloc = wm + mi * 16 + quad * 4 + r;
      long row = mb + rloc;
      float s = 0.f, ss = 0.f;
#pragma unroll
      for (int ni = 0; ni < 4; ni++) {
        int col = wn + ni * 16 + fr;
        float v = acc[mi][ni][r] + bv[ni] + b2f(resid[row * DD + col]);
        acc[mi][ni][r] = v;
        s += v;
        ss += v * v;
      }
      s += __shfl_xor(s, 1); ss += __shfl_xor(ss, 1);
      s += __shfl_xor(s, 2); ss += __shfl_xor(ss, 2);
      s += __shfl_xor(s, 4); ss += __shfl_xor(ss, 4);
      s += __shfl_xor(s, 8); ss += __shfl_xor(ss, 8);
      if (fr == 0) {
        s1[wn >> 6][rloc] = s;
        s2[wn >> 6][rloc] = ss;
      }
    }
  }
  __syncthreads();

#pragma unroll
  for (int mi = 0; mi < 2; mi++) {
#pragma unroll
    for (int r = 0; r < 4; r++) {
      int rloc = wm + mi * 16 + quad * 4 + r;
      long row = mb + rloc;
      float sum = s1[0][rloc] + s1[1][rloc];
      float sumsq = s2[0][rloc] + s2[1][rloc];
      float mean = sum * (1.f / 128.f);
      float var = sumsq * (1.f / 128.f) - mean * mean;
      float rstd = rsqrtf(var + 1e-5f);
#pragma unroll
      for (int ni = 0; ni < 4; ni++) {
        int col = wn + ni * 16 + fr;
        float o = (acc[mi][ni][r] - mean) * rstd * gv[ni] + be[ni];
        outB[row * DD + col] = f2b(o);
      }
    }
  }
}

// ---------------------------------------------------------------------------
// Fused QKV-projection + flash attention (verified round 9).
// ---------------------------------------------------------------------------
__global__ __launch_bounds__(256, 2) void qkv_attn(
    const u16* __restrict__ xb, const u16* __restrict__ qkvW,
    const float* __restrict__ bq, const float* __restrict__ bk,
    const float* __restrict__ bv, u16* __restrict__ Og) {
  const int bh = blockIdx.x;
  const int b = bh >> 3, h = bh & 7;
  __shared__ u16 Ks[512 * 24];
  __shared__ u16 Vt[16 * 520];
  __shared__ u16 Qs[512 * 24];
  const int t = threadIdx.x;
  const int w = t >> 6, lane = t & 63;
  const int fr = lane & 15, quad = lane >> 4;
  const long obase = ((long)b * SS) * DD + h * 16;
  const u16* xrow = xb + (long)b * SS * DD;

  const u16* Wq_h = qkvW + (h * 16) * 128;
  const u16* Wk_h = qkvW + 16384 + (h * 16) * 128;
  const u16* Wv_h = qkvW + 32768 + (h * 16) * 128;
  bf16x8 wqf[4], wkf[4], wvf[4];
#pragma unroll
  for (int c = 0; c < 4; c++) {
    wqf[c] = *(const bf16x8*)&Wq_h[fr * 128 + c * 32 + quad * 8];
    wkf[c] = *(const bf16x8*)&Wk_h[fr * 128 + c * 32 + quad * 8];
    wvf[c] = *(const bf16x8*)&Wv_h[fr * 128 + c * 32 + quad * 8];
  }
  const float bqv = bq[h * 16 + fr];
  const float bkv = bk[h * 16 + fr];
  const float bvv = bv[h * 16 + fr];
  const f32x4 z4 = {0.f, 0.f, 0.f, 0.f};

  for (int tile = w; tile < 32; tile += 4) {
    const int t0 = tile * 16;
    bf16x8 af[4];
#pragma unroll
    for (int c = 0; c < 4; c++)
      af[c] = *(const bf16x8*)&xrow[(t0 + fr) * 128 + c * 32 + quad * 8];
    f32x4 qa = z4, ka = z4, va = z4;
#pragma unroll
    for (int c = 0; c < 4; c++) {
      qa = __builtin_amdgcn_mfma_f32_16x16x32_bf16(af[c], wqf[c], qa, 0, 0, 0);
      ka = __builtin_amdgcn_mfma_f32_16x16x32_bf16(af[c], wkf[c], ka, 0, 0, 0);
      va = __builtin_amdgcn_mfma_f32_16x16x32_bf16(af[c], wvf[c], va, 0, 0, 0);
    }
#pragma unroll
    for (int r = 0; r < 4; r++) {
      int row = t0 + quad * 4 + r;
      Qs[row * 24 + fr] = f2b(qa[r] + bqv);
      Ks[row * 24 + fr] = f2b(ka[r] + bkv);
      Vt[fr * 520 + row] = f2b(va[r] + bvv);
    }
  }
  __syncthreads();

  const float scale = 0.25f;
  const int addrA = (((quad & 1) * 32) + fr) * 4;
  const int addrB = addrA + 64;
  const bool loTile = (quad < 2);

  for (int qt = w; qt < 32; qt += 4) {
    const int q0 = qt * 16;
    bf16x8 qf = {0, 0, 0, 0, 0, 0, 0, 0};
    if (quad < 2)
      qf = *(const bf16x8*)&Qs[(q0 + fr) * 24 + quad * 8];
    f32x4 oacc = {0.f, 0.f, 0.f, 0.f};
    float mrun = -1e30f, lrun = 0.f;

    for (int kt = 0; kt < 16; kt++) {
      const int k0 = kt * 32;
      bf16x8 kf0 = {0, 0, 0, 0, 0, 0, 0, 0};
      bf16x8 kf1 = {0, 0, 0, 0, 0, 0, 0, 0};
      if (quad < 2) {
        kf0 = *(const bf16x8*)&Ks[(k0 + fr) * 24 + quad * 8];
        kf1 = *(const bf16x8*)&Ks[(k0 + 16 + fr) * 24 + quad * 8];
      }
      f32x4 slo = __builtin_amdgcn_mfma_f32_16x16x32_bf16(kf0, qf, z4, 0, 0, 0);
      f32x4 shi = __builtin_amdgcn_mfma_f32_16x16x32_bf16(kf1, qf, z4, 0, 0, 0);
      float s[8];
#pragma unroll
      for (int r = 0; r < 4; r++) {
        s[r] = slo[r] * scale;
        s[4 + r] = shi[r] * scale;
      }
      float mx = s[0];
#pragma unroll
      for (int r = 1; r < 8; r++) mx = fmaxf(mx, s[r]);
      mx = fmaxf(mx, __shfl_xor(mx, 16));
      mx = fmaxf(mx, __shfl_xor(mx, 32));
      float nm = fmaxf(mrun, mx);
      float alpha = __expf(mrun - nm);
      mrun = nm;
      float p[8], rs = 0.f;
#pragma unroll
      for (int r = 0; r < 8; r++) {
        p[r] = __expf(s[r] - nm);
        rs += p[r];
      }
      rs += __shfl_xor(rs, 16);
      rs += __shfl_xor(rs, 32);
      lrun = lrun * alpha + rs;
#pragma unroll
      for (int r = 0; r < 4; r++) oacc[r] *= alpha;

      int pk0 = ((int)f2b(p[1]) << 16) | f2b(p[0]);
      int pk1 = ((int)f2b(p[3]) << 16) | f2b(p[2]);
      int pk2 = ((int)f2b(p[5]) << 16) | f2b(p[4]);
      int pk3 = ((int)f2b(p[7]) << 16) | f2b(p[6]);
      int B0a = __builtin_amdgcn_ds_bpermute(addrA, pk0);
      int B0b = __builtin_amdgcn_ds_bpermute(addrA, pk2);
      int B1a = __builtin_amdgcn_ds_bpermute(addrA, pk1);
      int B1b = __builtin_amdgcn_ds_bpermute(addrA, pk3);
      int B2a = __builtin_amdgcn_ds_bpermute(addrB, pk0);
      int B2b = __builtin_amdgcn_ds_bpermute(addrB, pk2);
      int B3a = __builtin_amdgcn_ds_bpermute(addrB, pk1);
      int B3b = __builtin_amdgcn_ds_bpermute(addrB, pk3);
      union { int i[4]; bf16x8 v; } pu;
      pu.i[0] = loTile ? B0a : B0b;
      pu.i[1] = loTile ? B1a : B1b;
      pu.i[2] = loTile ? B2a : B2b;
      pu.i[3] = loTile ? B3a : B3b;
      bf16x8 vf = *(const bf16x8*)&Vt[fr * 520 + k0 + quad * 8];
      oacc = __builtin_amdgcn_mfma_f32_16x16x32_bf16(vf, pu.v, oacc, 0, 0, 0);
    }

    float inv = __fdividef(1.f, lrun);
    ushort4 o;
    o.x = f2b(oacc[0] * inv);
    o.y = f2b(oacc[1] * inv);
    o.z = f2b(oacc[2] * inv);
    o.w = f2b(oacc[3] * inv);
    *(ushort4*)&Og[obase + (long)(q0 + fr) * DD + quad * 4] = o;
  }
}

// ---------------------------------------------------------------------------
// Fused mean-pool + classifier.
// ---------------------------------------------------------------------------
__global__ __launch_bounds__(128) void pool_cls(
    const u16* __restrict__ X, const float* __restrict__ W1,
    const float* __restrict__ b1, const float* __restrict__ W2,
    const float* __restrict__ b2, float* __restrict__ L) {
  const int b = blockIdx.x, t = threadIdx.x;
  __shared__ float sp[128];
  __shared__ float sh[64];
  float acc = 0.f;
  for (int s = 0; s < SS; s++) acc += b2f(X[((long)b * SS + s) * DD + t]);
  sp[t] = acc * (1.f / 512.f);
  __syncthreads();
  if (t < 64) {
    float a = b1[t];
    for (int k = 0; k < 128; k++) a += sp[k] * W1[k * 64 + t];
    sh[t] = fmaxf(a, 0.f);
  }
  __syncthreads();
  if (t < 5) {
    float a2 = b2[t];
    for (int k = 0; k < 64; k++) a2 += sh[k] * W2[k * 5 + t];
    L[b * 5 + t] = a2;
  }
}

// ---------------------------------------------------------------------------
extern "C" void kernel_launch(void* const* d_in, const int* in_sizes, int n_in,
                              void* d_out, int out_size, void* d_ws, size_t ws_size,
                              hipStream_t stream) {
  const float* ts    = (const float*)d_in[0];
  const float* noise = (const float*)d_in[2];
  const float* dW1   = (const float*)d_in[3];
  const float* db1   = (const float*)d_in[4];
  const float* dW2   = (const float*)d_in[5];
  const float* db2   = (const float*)d_in[6];
  const float* dW3   = (const float*)d_in[7];
  const float* db3   = (const float*)d_in[8];
  const float* gW1   = (const float*)d_in[9];
  const float* gb1   = (const float*)d_in[10];
  const float* gW2   = (const float*)d_in[11];
  const float* gb2   = (const float*)d_in[12];
  const float* mind  = (const float*)d_in[13];
  const float* maxd  = (const float*)d_in[14];
  const float* in_W  = (const float*)d_in[15];
  const float* in_b  = (const float*)d_in[16];
  const float* Wq    = (const float*)d_in[17];
  const float* bq    = (const float*)d_in[18];
  const float* Wk    = (const float*)d_in[19];
  const float* bk    = (const float*)d_in[20];
  const float* Wv    = (const float*)d_in[21];
  const float* bv    = (const float*)d_in[22];
  const float* Wo    = (const float*)d_in[23];
  const float* bo    = (const float*)d_in[24];
  const float* ln1s  = (const float*)d_in[25];
  const float* ln1b  = (const float*)d_in[26];
  const float* fW1   = (const float*)d_in[27];
  const float* fb1   = (const float*)d_in[28];
  const float* fW2   = (const float*)d_in[29];
  const float* fb2   = (const float*)d_in[30];
  const float* ln2s  = (const float*)d_in[31];
  const float* ln2b  = (const float*)d_in[32];
  const float* cW1   = (const float*)d_in[33];
  const float* cb1   = (const float*)d_in[34];
  const float* cW2   = (const float*)d_in[35];
  const float* cb2   = (const float*)d_in[36];

  float* logits = (float*)d_out;
  float* sde    = logits + BB * 5;

  char* W = (char*)d_ws;
  u16*  bxb    = (u16*)(W);                   //  8 MB bf16 x (residual stream)
  u16*  bh     = (u16*)(W + (8u << 20));      // 32 MB bf16 FFN hidden
  u16*  bob    = (u16*)(W + (40u << 20));     //  8 MB bf16 attn out
  u16*  bsb    = (u16*)(W + (48u << 20));     //  4 MB bf16 sde feats
  u16*  wts    = (u16*)(W + (52u << 20));     // ~1.5 MB bf16 weights

  u16* inWt  = wts;                 // [128][64]
  u16* qkvWt = inWt + 8192;         // [4][3][128][128]
  u16* Wot   = qkvWt + 196608;      // [4][128][128]
  u16* fW1t  = Wot + 65536;         // [4][512][128]
  u16* fW2t  = fW1t + 262144;       // [4][128][512]

  prep_weights<<<dim3(64, 4, 7), 256, 0, stream>>>(in_W, Wq, Wk, Wv, Wo, fW1, fW2,
                                                   inWt, qkvWt, Wot, fW1t, fW2t);

  sde_kernel<<<64, 1024, 0, stream>>>(ts, noise, dW1, db1, dW2, db2, dW3, db3,
                                      gW1, gb1, gW2, gb2, mind, maxd, sde, bsb);

  mfma_gemm<3><<<dim3(2, 256), 256, 0, stream>>>(bsb, inWt, in_b, bxb, 64, 128);

  for (int l = 0; l < 4; l++) {
    qkv_attn<<<BB * NHD, 256, 0, stream>>>(bxb, qkvWt + l * 49152,
                                           bq + l * DD, bk + l * DD, bv + l * DD,
                                           bob);
    gemm_ln<<<512, 256, 0, stream>>>(bob, Wot + l * 16384, bo + l * DD, bxb,
                                     ln1s + l * DD, ln1b + l * DD, bxb, 128);
    mfma_gemm<1><<<dim3(8, 256), 256, 0, stream>>>(bxb, fW1t + l * 65536,
                                                   fb1 + l * 512, bh, 128, 512);
    gemm_ln<<<512, 256, 0, stream>>>(bh, fW2t + l * 65536, fb2 + l * DD, bxb,
                                     ln2s + l * DD, ln2b + l * DD, bxb, 512);
  }

  pool_cls<<<BB, 128, 0, stream>>>(bxb, cW1, cb1, cW2, cb2, logits);
}

// Round 13
// 1262.333 us; speedup vs baseline: 1.5412x; 1.0545x over previous
//
#include <hip/hip_runtime.h>
#include <hip/hip_bf16.h>
#include <math.h>

#define BB 64
#define SS 512
#define HH 64
#define DD 128
#define NHD 8
#define ROWS (BB*SS)   // 32768

typedef unsigned short u16;
typedef __attribute__((ext_vector_type(8))) short bf16x8;
typedef __attribute__((ext_vector_type(4))) float f32x4;

__device__ __forceinline__ u16 f2b(float f) {
  union { float f; unsigned u; } x; x.f = f;
  unsigned r = x.u + 0x7fffu + ((x.u >> 16) & 1u);
  return (u16)(r >> 16);
}

__device__ __forceinline__ float b2f(u16 u) {
  return __uint_as_float(((unsigned)u) << 16);
}

__device__ __forceinline__ float fast_tanh(float x) {
  float ax = fminf(fabsf(x), 15.f);
  float e = __expf(2.f * ax);
  float r = 1.f - __fdividef(2.f, e + 1.f);
  return copysignf(r, x);
}

__device__ __forceinline__ void barrier_lds() {
  __builtin_amdgcn_s_waitcnt(0xC07F);   // lgkmcnt(0) only
  __builtin_amdgcn_s_barrier();
}

// ---------------------------------------------------------------------------
// SDE scan (v6 — measured floor at ~583 us across 9 structural variants:
// 256/512/1024 thr, readlane, pairing, MFMA batching, barrier styles).
// 512 thr, stage A 2-way split, B 4-way, C 8-way, LDS-only barriers.
// Latency-bound: 511 serial steps x ~2740 cyc; HBM 0.4%, MFMA 0.
// ---------------------------------------------------------------------------
__global__ __launch_bounds__(512, 2) void sde_kernel(
    const float* __restrict__ ts, const float* __restrict__ noise,
    const float* __restrict__ dW1, const float* __restrict__ db1,
    const float* __restrict__ dW2, const float* __restrict__ db2,
    const float* __restrict__ dW3, const float* __restrict__ db3,
    const float* __restrict__ gW1, const float* __restrict__ gb1,
    const float* __restrict__ gW2, const float* __restrict__ gb2,
    const float* __restrict__ pmind, const float* __restrict__ pmaxd,
    float* __restrict__ out, u16* __restrict__ outB) {
  const int b = blockIdx.x, t = threadIdx.x;
  __shared__ float y_s[64];
  __shared__ float h1g1[256];
  __shared__ float h2s[64], gcs[64];
  __shared__ float tl_s[512], hs_s[512], sq_s[512];

  const float mind = fabsf(pmind[0]);
  const float maxd = fabsf(pmaxd[0]);

  const int oA = t >> 1, hA = t & 1;
  const int cA = oA & 127;
  const float* W1 = (oA < 128) ? dW1 : gW1;
  float wA[32];
#pragma unroll
  for (int k = 0; k < 32; k++) wA[k] = W1[(hA * 32 + k) * 128 + cA];
  const float wAt = W1[64 * 128 + cA];
  const float bA = ((oA < 128) ? db1 : gb1)[cA];

  const int oB = t >> 2, qB = t & 3;
  const int cB = oB & 63;
  const float* W2 = (oB < 64) ? dW2 : gW2;
  float wB[32];
#pragma unroll
  for (int k = 0; k < 32; k++) wB[k] = W2[(qB * 32 + k) * 64 + cB];
  const float bB = ((oB < 64) ? db2 : gb2)[cB];

  const int cC = t >> 3, qC = t & 7;
  float wC[8];
#pragma unroll
  for (int k = 0; k < 8; k++) wC[k] = dW3[(qC * 8 + k) * 64 + cC];
  const float bC = db3[cC];

  // prologue
  tl_s[t] = ts[t * 3];
  __syncthreads();
  if (t < 511) {
    float hh = tl_s[t + 1] - tl_s[t];
    hs_s[t] = hh;
    sq_s[t] = sqrtf(hh);
  }
  if (t < 64) {
    float y = 0.1f;
    if (t < 3) y = fminf(fmaxf(ts[b * 1536 + t], 0.01f), 10.f);
    y_s[t] = y;
    out[(long)b * 32768 + t] = y;
    outB[((long)b * 512) * 64 + t] = f2b(y);
  }
  float nz = noise[b * 64 + cC];
  __syncthreads();

  for (int i = 0; i < 511; i++) {
    float nzn = 0.f;
    if (i < 510) nzn = noise[(long)(i + 1) * 4096 + b * 64 + cC];
    const float tl = tl_s[i];
    const float hh = hs_s[i];
    const float sq = sq_s[i];

    // ---- stage A ----
    float a0 = 0.f, a1 = 0.f, a2 = 0.f, a3 = 0.f;
#pragma unroll
    for (int g = 0; g < 8; g++) {
      float4 yv = *(const float4*)&y_s[hA * 32 + g * 4];
      a0 += yv.x * wA[g * 4 + 0];
      a1 += yv.y * wA[g * 4 + 1];
      a2 += yv.z * wA[g * 4 + 2];
      a3 += yv.w * wA[g * 4 + 3];
    }
    float p1 = (a0 + a1) + (a2 + a3);
    if (hA == 0) p1 += tl * wAt + bA;
    p1 += __shfl_xor(p1, 1);
    if (hA == 0) h1g1[oA] = fast_tanh(p1);
    barrier_lds();                        // barrier 1

    // ---- stage B ----
    const float* srcB = h1g1 + ((oB < 64) ? 0 : 128) + qB * 32;
    float c0 = 0.f, c1 = 0.f, c2 = 0.f, c3 = 0.f;
#pragma unroll
    for (int g = 0; g < 8; g++) {
      float4 xv = *(const float4*)&srcB[g * 4];
      c0 += xv.x * wB[g * 4 + 0];
      c1 += xv.y * wB[g * 4 + 1];
      c2 += xv.z * wB[g * 4 + 2];
      c3 += xv.w * wB[g * 4 + 3];
    }
    float p2 = (c0 + c1) + (c2 + c3);
    p2 += __shfl_xor(p2, 1);
    p2 += __shfl_xor(p2, 2);
    if (qB == 0) {
      p2 += bB;
      if (oB < 64) {
        h2s[cB] = fast_tanh(p2);
      } else {
        gcs[cB] = fmaxf(p2, 0.f) + __logf(1.f + __expf(-fabsf(p2))) + mind;
      }
    }
    barrier_lds();                        // barrier 2

    // ---- stage C ----
    float d0 = 0.f, d1 = 0.f;
#pragma unroll
    for (int g = 0; g < 2; g++) {
      float4 hv = *(const float4*)&h2s[qC * 8 + g * 4];
      d0 += hv.x * wC[g * 4 + 0];
      d0 += hv.y * wC[g * 4 + 1];
      d1 += hv.z * wC[g * 4 + 2];
      d1 += hv.w * wC[g * 4 + 3];
    }
    float p3 = d0 + d1;
    p3 += __shfl_xor(p3, 1);
    p3 += __shfl_xor(p3, 2);
    p3 += __shfl_xor(p3, 4);
    if (qC == 0) {
      float dc = fminf(fmaxf(p3 + bC, -maxd), maxd);
      float yo = y_s[cC];
      float gg = gcs[cC] * fminf(fmaxf(yo, -10.f), 10.f);
      float yn = yo + dc * yo * hh + gg * nz * sq;
      yn = fminf(fmaxf(yn, 0.01f), 10.f);
      y_s[cC] = yn;
      out[(long)b * 32768 + (i + 1) * 64 + cC] = yn;
      outB[((long)b * 512 + i + 1) * 64 + cC] = f2b(yn);
    }
    nz = nzn;
    barrier_lds();                        // barrier 3
  }
}

// ---------------------------------------------------------------------------
__global__ __launch_bounds__(256) void prep_weights(
    const float* __restrict__ in_W, const float* __restrict__ Wq,
    const float* __restrict__ Wk, const float* __restrict__ Wv,
    const float* __restrict__ Wo, const float* __restrict__ fW1,
    const float* __restrict__ fW2,
    u16* __restrict__ inWt, u16* __restrict__ qkvWt, u16* __restrict__ Wot,
    u16* __restrict__ fW1t, u16* __restrict__ fW2t) {
  const int z = blockIdx.z, layer = blockIdx.y, tile = blockIdx.x;
  const float* src; u16* dst; int R, C, nl;
  switch (z) {
    case 0: src = in_W; dst = inWt; R = 64; C = 128; nl = 1; break;
    case 1: src = Wq + layer * 16384; dst = qkvWt + layer * 49152; R = 128; C = 128; nl = 4; break;
    case 2: src = Wk + layer * 16384; dst = qkvWt + layer * 49152 + 16384; R = 128; C = 128; nl = 4; break;
    case 3: src = Wv + layer * 16384; dst = qkvWt + layer * 49152 + 32768; R = 128; C = 128; nl = 4; break;
    case 4: src = Wo + layer * 16384; dst = Wot + layer * 16384; R = 128; C = 128; nl = 4; break;
    case 5: src = fW1 + layer * 65536; dst = fW1t + layer * 65536; R = 128; C = 512; nl = 4; break;
    default: src = fW2 + layer * 65536; dst = fW2t + layer * 65536; R = 512; C = 128; nl = 4; break;
  }
  const int nt = (R / 32) * (C / 32);
  if (layer >= nl || tile >= nt) return;
  const int tpr = C / 32;
  const int r0 = (tile / tpr) * 32, c0 = (tile % tpr) * 32;
  __shared__ float tl[32][33];
  const int tx = threadIdx.x & 31, ty = threadIdx.x >> 5;
#pragma unroll
  for (int p = 0; p < 4; p++)
    tl[ty + 8 * p][tx] = src[(long)(r0 + ty + 8 * p) * C + c0 + tx];
  __syncthreads();
#pragma unroll
  for (int p = 0; p < 4; p++)
    dst[(long)(c0 + ty + 8 * p) * R + r0 + tx] = f2b(tl[tx][ty + 8 * p]);
}

// ---------------------------------------------------------------------------
// bf16 MFMA GEMM. MODE 1: bf16+relu. MODE 3: bf16.
// ---------------------------------------------------------------------------
template <int MODE>
__global__ __launch_bounds__(256) void mfma_gemm(
    const u16* __restrict__ A, const u16* __restrict__ Bt,
    const float* __restrict__ bias, u16* __restrict__ outB, int K, int N) {
  __shared__ u16 As[128 * 40];
  __shared__ u16 Bs[64 * 40];
  const int t = threadIdx.x;
  const int nb = blockIdx.x * 64;
  const long mb = (long)blockIdx.y * 128;
  const int lane = t & 63, wave = t >> 6;
  const int wm = (wave >> 1) * 64, wn = (wave & 1) * 32;
  const int fr = lane & 15, quad = lane >> 4;

  f32x4 zero = {0.f, 0.f, 0.f, 0.f};
  f32x4 acc[4][2];
#pragma unroll
  for (int mi = 0; mi < 4; mi++)
#pragma unroll
    for (int ni = 0; ni < 2; ni++) acc[mi][ni] = zero;

  for (int k0 = 0; k0 < K; k0 += 32) {
#pragma unroll
    for (int p = 0; p < 2; p++) {
      int idx = t + p * 256, row = idx >> 2, seg = idx & 3;
      int4 v = *(const int4*)&A[(mb + row) * K + k0 + seg * 8];
      *(int4*)&As[row * 40 + seg * 8] = v;
    }
    {
      int row = t >> 2, seg = t & 3;
      int4 v = *(const int4*)&Bt[(long)(nb + row) * K + k0 + seg * 8];
      *(int4*)&Bs[row * 40 + seg * 8] = v;
    }
    __syncthreads();
    bf16x8 af[4], bfr[2];
#pragma unroll
    for (int mi = 0; mi < 4; mi++)
      af[mi] = *(const bf16x8*)&As[(wm + mi * 16 + fr) * 40 + quad * 8];
#pragma unroll
    for (int ni = 0; ni < 2; ni++)
      bfr[ni] = *(const bf16x8*)&Bs[(wn + ni * 16 + fr) * 40 + quad * 8];
#pragma unroll
    for (int mi = 0; mi < 4; mi++)
#pragma unroll
      for (int ni = 0; ni < 2; ni++)
        acc[mi][ni] = __builtin_amdgcn_mfma_f32_16x16x32_bf16(
            af[mi], bfr[ni], acc[mi][ni], 0, 0, 0);
    __syncthreads();
  }

#pragma unroll
  for (int mi = 0; mi < 4; mi++)
#pragma unroll
    for (int ni = 0; ni < 2; ni++) {
      int col = nb + wn + ni * 16 + fr;
      float bv = bias[col];
#pragma unroll
      for (int r = 0; r < 4; r++) {
        long row = mb + wm + mi * 16 + quad * 4 + r;
        float v = acc[mi][ni][r] + bv;
        if (MODE == 1) {
          outB[row * N + col] = f2b(fmaxf(v, 0.f));
        } else {
          outB[row * N + col] = f2b(v);
        }
      }
    }
}

// ---------------------------------------------------------------------------
// Fused GEMM + residual(bf16) + LayerNorm -> bf16. Tile 64x128, 512 blocks.
// ---------------------------------------------------------------------------
__global__ __launch_bounds__(256) void gemm_ln(
    const u16* __restrict__ A, const u16* __restrict__ Bt,
    const float* __restrict__ bias, const u16* __restrict__ resid,
    const float* __restrict__ gamma, const float* __restrict__ beta,
    u16* __restrict__ outB, int K) {
  __shared__ u16 As[64 * 40];
  __shared__ u16 Bs[128 * 40];
  __shared__ float s1[2][64], s2[2][64];
  const int t = threadIdx.x;
  const long mb = (long)blockIdx.x * 64;
  const int lane = t & 63, wave = t >> 6;
  const int wm = (wave >> 1) * 32, wn = (wave & 1) * 64;
  const int fr = lane & 15, quad = lane >> 4;

  f32x4 zero = {0.f, 0.f, 0.f, 0.f};
  f32x4 acc[2][4];
#pragma unroll
  for (int mi = 0; mi < 2; mi++)
#pragma unroll
    for (int ni = 0; ni < 4; ni++) acc[mi][ni] = zero;

  for (int k0 = 0; k0 < K; k0 += 32) {
    {
      int row = t >> 2, seg = t & 3;
      *(int4*)&As[row * 40 + seg * 8] =
          *(const int4*)&A[(mb + row) * K + k0 + seg * 8];
    }
#pragma unroll
    for (int p = 0; p < 2; p++) {
      int idx = t + p * 256, row = idx >> 2, seg = idx & 3;
      *(int4*)&Bs[row * 40 + seg * 8] =
          *(const int4*)&Bt[(long)row * K + k0 + seg * 8];
    }
    __syncthreads();
    bf16x8 af[2], bfr[4];
#pragma unroll
    for (int mi = 0; mi < 2; mi++)
      af[mi] = *(const bf16x8*)&As[(wm + mi * 16 + fr) * 40 + quad * 8];
#pragma unroll
    for (int ni = 0; ni < 4; ni++)
      bfr[ni] = *(const bf16x8*)&Bs[(wn + ni * 16 + fr) * 40 + quad * 8];
#pragma unroll
    for (int mi = 0; mi < 2; mi++)
#pragma unroll
      for (int ni = 0; ni < 4; ni++)
        acc[mi][ni] = __builtin_amdgcn_mfma_f32_16x16x32_bf16(
            af[mi], bfr[ni], acc[mi][ni], 0, 0, 0);
    __syncthreads();
  }

  float bv[4], gv[4], be[4];
#pragma unroll
  for (int ni = 0; ni < 4; ni++) {
    int col = wn + ni * 16 + fr;
    bv[ni] = bias[col];
    gv[ni] = gamma[col];
    be[ni] = beta[col];
  }

#pragma unroll
  for (int mi = 0; mi < 2; mi++) {
#pragma unroll
    for (int r = 0; r < 4; r++) {
      int rloc = wm + mi * 16 + quad * 4 + r;
      long row = mb + rloc;
      float s = 0.f, ss = 0.f;
#pragma unroll
      for (int ni = 0; ni < 4; ni++) {
        int col = wn + ni * 16 + fr;
        float v = acc[mi][ni][r] + bv[ni] + b2f(resid[row * DD + col]);
        acc[mi][ni][r] = v;
        s += v;
        ss += v * v;
      }
      s += __shfl_xor(s, 1); ss += __shfl_xor(ss, 1);
      s += __shfl_xor(s, 2); ss += __shfl_xor(ss, 2);
      s += __shfl_xor(s, 4); ss += __shfl_xor(ss, 4);
      s += __shfl_xor(s, 8); ss += __shfl_xor(ss, 8);
      if (fr == 0) {
        s1[wn >> 6][rloc] = s;
        s2[wn >> 6][rloc] = ss;
      }
    }
  }
  __syncthreads();

#pragma unroll
  for (int mi = 0; mi < 2; mi++) {
#pragma unroll
    for (int r = 0; r < 4; r++) {
      int rloc = wm + mi * 16 + quad * 4 + r;
      long row = mb + rloc;
      float sum = s1[0][rloc] + s1[1][rloc];
      float sumsq = s2[0][rloc] + s2[1][rloc];
      float mean = sum * (1.f / 128.f);
      float var = sumsq * (1.f / 128.f) - mean * mean;
      float rstd = rsqrtf(var + 1e-5f);
#pragma unroll
      for (int ni = 0; ni < 4; ni++) {
        int col = wn + ni * 16 + fr;
        float o = (acc[mi][ni][r] - mean) * rstd * gv[ni] + be[ni];
        outB[row * DD + col] = f2b(o);
      }
    }
  }
}

// ---------------------------------------------------------------------------
// Fused QKV-projection + flash attention (verified round 9).
// ---------------------------------------------------------------------------
__global__ __launch_bounds__(256, 2) void qkv_attn(
    const u16* __restrict__ xb, const u16* __restrict__ qkvW,
    const float* __restrict__ bq, const float* __restrict__ bk,
    const float* __restrict__ bv, u16* __restrict__ Og) {
  const int bh = blockIdx.x;
  const int b = bh >> 3, h = bh & 7;
  __shared__ u16 Ks[512 * 24];
  __shared__ u16 Vt[16 * 520];
  __shared__ u16 Qs[512 * 24];
  const int t = threadIdx.x;
  const int w = t >> 6, lane = t & 63;
  const int fr = lane & 15, quad = lane >> 4;
  const long obase = ((long)b * SS) * DD + h * 16;
  const u16* xrow = xb + (long)b * SS * DD;

  const u16* Wq_h = qkvW + (h * 16) * 128;
  const u16* Wk_h = qkvW + 16384 + (h * 16) * 128;
  const u16* Wv_h = qkvW + 32768 + (h * 16) * 128;
  bf16x8 wqf[4], wkf[4], wvf[4];
#pragma unroll
  for (int c = 0; c < 4; c++) {
    wqf[c] = *(const bf16x8*)&Wq_h[fr * 128 + c * 32 + quad * 8];
    wkf[c] = *(const bf16x8*)&Wk_h[fr * 128 + c * 32 + quad * 8];
    wvf[c] = *(const bf16x8*)&Wv_h[fr * 128 + c * 32 + quad * 8];
  }
  const float bqv = bq[h * 16 + fr];
  const float bkv = bk[h * 16 + fr];
  const float bvv = bv[h * 16 + fr];
  const f32x4 z4 = {0.f, 0.f, 0.f, 0.f};

  for (int tile = w; tile < 32; tile += 4) {
    const int t0 = tile * 16;
    bf16x8 af[4];
#pragma unroll
    for (int c = 0; c < 4; c++)
      af[c] = *(const bf16x8*)&xrow[(t0 + fr) * 128 + c * 32 + quad * 8];
    f32x4 qa = z4, ka = z4, va = z4;
#pragma unroll
    for (int c = 0; c < 4; c++) {
      qa = __builtin_amdgcn_mfma_f32_16x16x32_bf16(af[c], wqf[c], qa, 0, 0, 0);
      ka = __builtin_amdgcn_mfma_f32_16x16x32_bf16(af[c], wkf[c], ka, 0, 0, 0);
      va = __builtin_amdgcn_mfma_f32_16x16x32_bf16(af[c], wvf[c], va, 0, 0, 0);
    }
#pragma unroll
    for (int r = 0; r < 4; r++) {
      int row = t0 + quad * 4 + r;
      Qs[row * 24 + fr] = f2b(qa[r] + bqv);
      Ks[row * 24 + fr] = f2b(ka[r] + bkv);
      Vt[fr * 520 + row] = f2b(va[r] + bvv);
    }
  }
  __syncthreads();

  const float scale = 0.25f;
  const int addrA = (((quad & 1) * 32) + fr) * 4;
  const int addrB = addrA + 64;
  const bool loTile = (quad < 2);

  for (int qt = w; qt < 32; qt += 4) {
    const int q0 = qt * 16;
    bf16x8 qf = {0, 0, 0, 0, 0, 0, 0, 0};
    if (quad < 2)
      qf = *(const bf16x8*)&Qs[(q0 + fr) * 24 + quad * 8];
    f32x4 oacc = {0.f, 0.f, 0.f, 0.f};
    float mrun = -1e30f, lrun = 0.f;

    for (int kt = 0; kt < 16; kt++) {
      const int k0 = kt * 32;
      bf16x8 kf0 = {0, 0, 0, 0, 0, 0, 0, 0};
      bf16x8 kf1 = {0, 0, 0, 0, 0, 0, 0, 0};
      if (quad < 2) {
        kf0 = *(const bf16x8*)&Ks[(k0 + fr) * 24 + quad * 8];
        kf1 = *(const bf16x8*)&Ks[(k0 + 16 + fr) * 24 + quad * 8];
      }
      f32x4 slo = __builtin_amdgcn_mfma_f32_16x16x32_bf16(kf0, qf, z4, 0, 0, 0);
      f32x4 shi = __builtin_amdgcn_mfma_f32_16x16x32_bf16(kf1, qf, z4, 0, 0, 0);
      float s[8];
#pragma unroll
      for (int r = 0; r < 4; r++) {
        s[r] = slo[r] * scale;
        s[4 + r] = shi[r] * scale;
      }
      float mx = s[0];
#pragma unroll
      for (int r = 1; r < 8; r++) mx = fmaxf(mx, s[r]);
      mx = fmaxf(mx, __shfl_xor(mx, 16));
      mx = fmaxf(mx, __shfl_xor(mx, 32));
      float nm = fmaxf(mrun, mx);
      float alpha = __expf(mrun - nm);
      mrun = nm;
      float p[8], rs = 0.f;
#pragma unroll
      for (int r = 0; r < 8; r++) {
        p[r] = __expf(s[r] - nm);
        rs += p[r];
      }
      rs += __shfl_xor(rs, 16);
      rs += __shfl_xor(rs, 32);
      lrun = lrun * alpha + rs;
#pragma unroll
      for (int r = 0; r < 4; r++) oacc[r] *= alpha;

      int pk0 = ((int)f2b(p[1]) << 16) | f2b(p[0]);
      int pk1 = ((int)f2b(p[3]) << 16) | f2b(p[2]);
      int pk2 = ((int)f2b(p[5]) << 16) | f2b(p[4]);
      int pk3 = ((int)f2b(p[7]) << 16) | f2b(p[6]);
      int B0a = __builtin_amdgcn_ds_bpermute(addrA, pk0);
      int B0b = __builtin_amdgcn_ds_bpermute(addrA, pk2);
      int B1a = __builtin_amdgcn_ds_bpermute(addrA, pk1);
      int B1b = __builtin_amdgcn_ds_bpermute(addrA, pk3);
      int B2a = __builtin_amdgcn_ds_bpermute(addrB, pk0);
      int B2b = __builtin_amdgcn_ds_bpermute(addrB, pk2);
      int B3a = __builtin_amdgcn_ds_bpermute(addrB, pk1);
      int B3b = __builtin_amdgcn_ds_bpermute(addrB, pk3);
      union { int i[4]; bf16x8 v; } pu;
      pu.i[0] = loTile ? B0a : B0b;
      pu.i[1] = loTile ? B1a : B1b;
      pu.i[2] = loTile ? B2a : B2b;
      pu.i[3] = loTile ? B3a : B3b;
      bf16x8 vf = *(const bf16x8*)&Vt[fr * 520 + k0 + quad * 8];
      oacc = __builtin_amdgcn_mfma_f32_16x16x32_bf16(vf, pu.v, oacc, 0, 0, 0);
    }

    float inv = __fdividef(1.f, lrun);
    ushort4 o;
    o.x = f2b(oacc[0] * inv);
    o.y = f2b(oacc[1] * inv);
    o.z = f2b(oacc[2] * inv);
    o.w = f2b(oacc[3] * inv);
    *(ushort4*)&Og[obase + (long)(q0 + fr) * DD + quad * 4] = o;
  }
}

// ---------------------------------------------------------------------------
// Fused mean-pool + classifier.
// ---------------------------------------------------------------------------
__global__ __launch_bounds__(128) void pool_cls(
    const u16* __restrict__ X, const float* __restrict__ W1,
    const float* __restrict__ b1, const float* __restrict__ W2,
    const float* __restrict__ b2, float* __restrict__ L) {
  const int b = blockIdx.x, t = threadIdx.x;
  __shared__ float sp[128];
  __shared__ float sh[64];
  float acc = 0.f;
  for (int s = 0; s < SS; s++) acc += b2f(X[((long)b * SS + s) * DD + t]);
  sp[t] = acc * (1.f / 512.f);
  __syncthreads();
  if (t < 64) {
    float a = b1[t];
    for (int k = 0; k < 128; k++) a += sp[k] * W1[k * 64 + t];
    sh[t] = fmaxf(a, 0.f);
  }
  __syncthreads();
  if (t < 5) {
    float a2 = b2[t];
    for (int k = 0; k < 64; k++) a2 += sh[k] * W2[k * 5 + t];
    L[b * 5 + t] = a2;
  }
}

// ---------------------------------------------------------------------------
extern "C" void kernel_launch(void* const* d_in, const int* in_sizes, int n_in,
                              void* d_out, int out_size, void* d_ws, size_t ws_size,
                              hipStream_t stream) {
  const float* ts    = (const float*)d_in[0];
  const float* noise = (const float*)d_in[2];
  const float* dW1   = (const float*)d_in[3];
  const float* db1   = (const float*)d_in[4];
  const float* dW2   = (const float*)d_in[5];
  const float* db2   = (const float*)d_in[6];
  const float* dW3   = (const float*)d_in[7];
  const float* db3   = (const float*)d_in[8];
  const float* gW1   = (const float*)d_in[9];
  const float* gb1   = (const float*)d_in[10];
  const float* gW2   = (const float*)d_in[11];
  const float* gb2   = (const float*)d_in[12];
  const float* mind  = (const float*)d_in[13];
  const float* maxd  = (const float*)d_in[14];
  const float* in_W  = (const float*)d_in[15];
  const float* in_b  = (const float*)d_in[16];
  const float* Wq    = (const float*)d_in[17];
  const float* bq    = (const float*)d_in[18];
  const float* Wk    = (const float*)d_in[19];
  const float* bk    = (const float*)d_in[20];
  const float* Wv    = (const float*)d_in[21];
  const float* bv    = (const float*)d_in[22];
  const float* Wo    = (const float*)d_in[23];
  const float* bo    = (const float*)d_in[24];
  const float* ln1s  = (const float*)d_in[25];
  const float* ln1b  = (const float*)d_in[26];
  const float* fW1   = (const float*)d_in[27];
  const float* fb1   = (const float*)d_in[28];
  const float* fW2   = (const float*)d_in[29];
  const float* fb2   = (const float*)d_in[30];
  const float* ln2s  = (const float*)d_in[31];
  const float* ln2b  = (const float*)d_in[32];
  const float* cW1   = (const float*)d_in[33];
  const float* cb1   = (const float*)d_in[34];
  const float* cW2   = (const float*)d_in[35];
  const float* cb2   = (const float*)d_in[36];

  float* logits = (float*)d_out;
  float* sde    = logits + BB * 5;

  char* W = (char*)d_ws;
  u16*  bxb    = (u16*)(W);                   //  8 MB bf16 x (residual stream)
  u16*  bh     = (u16*)(W + (8u << 20));      // 32 MB bf16 FFN hidden
  u16*  bob    = (u16*)(W + (40u << 20));     //  8 MB bf16 attn out
  u16*  bsb    = (u16*)(W + (48u << 20));     //  4 MB bf16 sde feats
  u16*  wts    = (u16*)(W + (52u << 20));     // ~1.5 MB bf16 weights

  u16* inWt  = wts;                 // [128][64]
  u16* qkvWt = inWt + 8192;         // [4][3][128][128]
  u16* Wot   = qkvWt + 196608;      // [4][128][128]
  u16* fW1t  = Wot + 65536;         // [4][512][128]
  u16* fW2t  = fW1t + 262144;       // [4][128][512]

  prep_weights<<<dim3(64, 4, 7), 256, 0, stream>>>(in_W, Wq, Wk, Wv, Wo, fW1, fW2,
                                                   inWt, qkvWt, Wot, fW1t, fW2t);

  sde_kernel<<<64, 512, 0, stream>>>(ts, noise, dW1, db1, dW2, db2, dW3, db3,
                                     gW1, gb1, gW2, gb2, mind, maxd, sde, bsb);

  mfma_gemm<3><<<dim3(2, 256), 256, 0, stream>>>(bsb, inWt, in_b, bxb, 64, 128);

  for (int l = 0; l < 4; l++) {
    qkv_attn<<<BB * NHD, 256, 0, stream>>>(bxb, qkvWt + l * 49152,
                                           bq + l * DD, bk + l * DD, bv + l * DD,
                                           bob);
    gemm_ln<<<512, 256, 0, stream>>>(bob, Wot + l * 16384, bo + l * DD, bxb,
                                     ln1s + l * DD, ln1b + l * DD, bxb, 128);
    mfma_gemm<1><<<dim3(8, 256), 256, 0, stream>>>(bxb, fW1t + l * 65536,
                                                   fb1 + l * 512, bh, 128, 512);
    gemm_ln<<<512, 256, 0, stream>>>(bh, fW2t + l * 65536, fb2 + l * DD, bxb,
                                     ln2s + l * DD, ln2b + l * DD, bxb, 512);
  }

  pool_cls<<<BB, 128, 0, stream>>>(bxb, cW1, cb1, cW2, cb2, logits);
}